// Round 14
// baseline (308.398 us; speedup 1.0000x reference)
//
#include <hip/hip_runtime.h>
#include <hip/hip_bf16.h>
#include <math.h>

typedef unsigned short u16;
typedef __bf16 bf16x8 __attribute__((ext_vector_type(8)));
typedef float  f32x4  __attribute__((ext_vector_type(4)));

#define DIMC 256
#define QSZ  56
#define WSZ  7
#define SSZ  3
#define LWIN 49
#define NWIN 64
#define HW   3136          // 56*56
#define NTOK 50176         // 16*3136
#define FFWD 1024
#define FCH  25088         // NTOK/2 ffn chunk rows
#define QKVP 776           // staged qkv row pitch in u16 (768 + 8 pad -> 1552 B)

__device__ __forceinline__ u16 f2bu(float f) {
    __hip_bfloat16 h = __float2bfloat16(f);
    return __builtin_bit_cast(u16, h);
}
__device__ __forceinline__ float bu2f(u16 u) {
    unsigned v = (unsigned)u << 16;
    return __builtin_bit_cast(float, v);
}
__device__ __forceinline__ void gload_lds16(const void* g, void* l) {
    __builtin_amdgcn_global_load_lds((const __attribute__((address_space(1))) void*)g,
                                     (__attribute__((address_space(3))) void*)l, 16, 0, 0);
}

__device__ __forceinline__ int region_of(int h) {
    return (h < 49) ? 0 : ((h < 53) ? 1 : 2);
}

// partitioned row m = ((b*64 + wi)*49 + p) -> flat token index (with roll by -3)
__device__ __forceinline__ int row2tok(int m) {
    int b  = m / (NWIN * LWIN);
    int r  = m - b * (NWIN * LWIN);
    int wi = r / LWIN;
    int p  = r - wi * LWIN;
    int wh = wi >> 3, ww = wi & 7;
    int ph = p / 7,   pw = p - ph * 7;
    int hr = wh * 7 + ph, wr = ww * 7 + pw;
    int hs = hr + SSZ; if (hs >= QSZ) hs -= QSZ;
    int ws2 = wr + SSZ; if (ws2 >= QSZ) ws2 -= QSZ;
    return b * HW + hs * QSZ + ws2;
}

// ---------------- weight transpose + bf16 convert: Wt[n][k] = bf16(W[k][n]) ---
__global__ __launch_bounds__(256) void k_wconv(const float* __restrict__ W,
        u16* __restrict__ Wt, int K, int N) {
    __shared__ float tile[32][33];
    int k0 = blockIdx.x * 32, n0 = blockIdx.y * 32;
    int tx = threadIdx.x & 31, ty = threadIdx.x >> 5;
    for (int kk = ty; kk < 32; kk += 8)
        tile[kk][tx] = W[(size_t)(k0 + kk) * N + n0 + tx];
    __syncthreads();
    for (int nn = ty; nn < 32; nn += 8)
        Wt[(size_t)(n0 + nn) * K + k0 + tx] = f2bu(tile[tx][nn]);
}

// ---------------- K1: BCHW -> token-major transpose + LN1 -> bf16 -------------
__global__ __launch_bounds__(256) void k_ln1(const float* __restrict__ x,
        const float* __restrict__ g, const float* __restrict__ be,
        u16* __restrict__ hln) {
    __shared__ float tile[32][257];
    __shared__ float msh[32], rsh[32];
    int blk = blockIdx.x;            // 16 * 98
    int b   = blk / 98;
    int hw0 = (blk - b * 98) * 32;
    int t   = threadIdx.x;
    int tx  = t & 31, ty = t >> 5;
    for (int c = ty; c < 256; c += 8)
        tile[tx][c] = x[(size_t)(b * 256 + c) * HW + hw0 + tx];
    __syncthreads();
    int row = t >> 3, sub = t & 7;
    float s = 0.f, sq = 0.f;
    for (int c = sub * 32; c < sub * 32 + 32; ++c) {
        float v = tile[row][c]; s += v; sq += v * v;
    }
    for (int o = 4; o; o >>= 1) { s += __shfl_down(s, o, 8); sq += __shfl_down(sq, o, 8); }
    if (sub == 0) {
        float m   = s * (1.f / 256.f);
        float var = sq * (1.f / 256.f) - m * m;
        msh[row] = m; rsh[row] = rsqrtf(var + 1e-5f);
    }
    __syncthreads();
    float gg = g[t], bb = be[t];
    for (int r2 = 0; r2 < 32; ++r2) {
        float v = tile[r2][t];
        hln[(size_t)(b * HW + hw0 + r2) * 256 + t] = f2bu((v - msh[r2]) * rsh[r2] * gg + bb);
    }
}

// ---------------- LN2 + residual: x1 = proj_out + transpose(x); h2 = LN(x1) ---
// po/x1b is IN-PLACE: holds proj_out (token-major bf16) on entry, x1 on exit.
__global__ __launch_bounds__(256) void k_ln2t(const float* __restrict__ x,
        u16* __restrict__ x1b, const float* __restrict__ g,
        const float* __restrict__ be, u16* __restrict__ h2) {
    __shared__ float tile[32][257];
    __shared__ float msh[32], rsh[32];
    int blk = blockIdx.x;            // 16 * 98
    int b   = blk / 98;
    int hw0 = (blk - b * 98) * 32;
    int t   = threadIdx.x;
    int tx  = t & 31, ty = t >> 5;
    for (int c = ty; c < 256; c += 8)
        tile[tx][c] = x[(size_t)(b * 256 + c) * HW + hw0 + tx];
    __syncthreads();
    size_t base = (size_t)b * HW + hw0;
    for (int r2 = 0; r2 < 32; ++r2) {
        float v = tile[r2][t] + bu2f(x1b[(base + r2) * 256 + t]);
        tile[r2][t] = v;
        x1b[(base + r2) * 256 + t] = f2bu(v);
    }
    __syncthreads();
    int row = t >> 3, sub = t & 7;
    float s = 0.f, sq = 0.f;
    for (int c = sub * 32; c < sub * 32 + 32; ++c) {
        float v = tile[row][c]; s += v; sq += v * v;
    }
    for (int o = 4; o; o >>= 1) { s += __shfl_down(s, o, 8); sq += __shfl_down(sq, o, 8); }
    if (sub == 0) {
        float m   = s * (1.f / 256.f);
        float var = sq * (1.f / 256.f) - m * m;
        msh[row] = m; rsh[row] = rsqrtf(var + 1e-5f);
    }
    __syncthreads();
    float gg = g[t], bb = be[t];
    for (int r2 = 0; r2 < 32; ++r2) {
        float v = tile[r2][t];
        h2[(base + r2) * 256 + t] = f2bu((v - msh[r2]) * rsh[r2] * gg + bb);
    }
}

// ---------------- MFMA bf16 GEMM, 256x128 tile, BK=32, 8 waves, 512 thr -------
// R10-verified 2-buffer depth-1 sync (barriers A+B, counted vmcnt(3));
// T2 swizzle (conflicts = 0, verified R13): pre-swizzled global source chunk
// kc = (t&3)^((t>>3)&3), swizzled read group kos.
template<int MODE>
__global__ __launch_bounds__(512) void k_mgemm(
        const u16* __restrict__ A, const u16* __restrict__ Bt,
        const float* __restrict__ bias, void* __restrict__ Cv,
        int K, int N, const void* __restrict__ extra,
        const float* __restrict__ extra2, int grow0) {
    __shared__ __align__(16) u16 As[2][256 * 32];   // 16 KB each
    __shared__ __align__(16) u16 Bs[2][128 * 32];   //  8 KB each
    const int m0 = blockIdx.x * 256, n0 = blockIdx.y * 128;
    const int t = threadIdx.x, lane = t & 63;
    const int wv = t >> 6, wr = wv >> 1, wc = wv & 1;   // wr 0..3, wc 0..1

    const int kc = (t & 3) ^ ((t >> 3) & 3);
    int ar0 = m0 + (t >> 2), ar1 = m0 + 128 + (t >> 2);
    if (MODE == 0) { ar0 = row2tok(ar0); ar1 = row2tok(ar1); }
    const u16* gA0 = A  + (size_t)ar0 * K + kc * 8;
    const u16* gA1 = A  + (size_t)ar1 * K + kc * 8;
    const u16* gB0 = Bt + (size_t)(n0 + (t >> 2)) * K + kc * 8;

    f32x4 acc[4][4] = {};
    const int ra = wr * 64 + (lane & 15);
    const int rb = wc * 64 + (lane & 15);
    const int kos = (((lane >> 4) ^ (lane >> 1)) & 3) * 8;  // swizzled read grp
    const int nIter = K >> 5;

    gload_lds16(gA0, As[0] + t * 8);
    gload_lds16(gA1, As[0] + 4096 + t * 8);
    gload_lds16(gB0, Bs[0] + t * 8);

    int cur = 0;
    for (int it = 0; it < nIter; ++it) {
        if (it + 1 < nIter) {
            const int k1 = (it + 1) << 5;
            gload_lds16(gA0 + k1, As[cur ^ 1] + t * 8);
            gload_lds16(gA1 + k1, As[cur ^ 1] + 4096 + t * 8);
            gload_lds16(gB0 + k1, Bs[cur ^ 1] + t * 8);
            asm volatile("s_waitcnt vmcnt(3)" ::: "memory");
        } else {
            asm volatile("s_waitcnt vmcnt(0)" ::: "memory");
        }
        __builtin_amdgcn_s_barrier();      // A: cur-stage LDS complete for all
        __builtin_amdgcn_sched_barrier(0);
        bf16x8 af[4], bfr[4];
#pragma unroll
        for (int i = 0; i < 4; ++i)
            af[i] = *(const bf16x8*)(As[cur] + (ra + i * 16) * 32 + kos);
#pragma unroll
        for (int j = 0; j < 4; ++j)
            bfr[j] = *(const bf16x8*)(Bs[cur] + (rb + ((j & 1) * 16 + (j >> 1) * 32)) * 32 + kos);
        asm volatile("s_waitcnt lgkmcnt(0)" ::: "memory");
        __builtin_amdgcn_sched_barrier(0);
        __builtin_amdgcn_s_barrier();      // B: buffer cur consumed -> reusable
#pragma unroll
        for (int i = 0; i < 4; ++i)
#pragma unroll
            for (int j = 0; j < 4; ++j)
                acc[i][j] = __builtin_amdgcn_mfma_f32_16x16x32_bf16(af[i], bfr[j], acc[i][j], 0, 0, 0);
        cur ^= 1;
    }

    const int rowb = m0 + wr * 64 + ((lane >> 4) * 4); // + i*16 + r

    if constexpr (MODE == 0) {
        u16* Cb = (u16*)Cv;
#pragma unroll
        for (int j = 0; j < 4; ++j) {
            int col = n0 + wc * 64 + ((j & 1) * 16 + (j >> 1) * 32) + (lane & 15);
            float bj = bias[col];
#pragma unroll
            for (int i = 0; i < 4; ++i) {
                int rw = rowb + i * 16;
#pragma unroll
                for (int r = 0; r < 4; ++r)
                    Cb[(size_t)(rw + r) * N + col] = f2bu(acc[i][j][r] + bj);
            }
        }
    } else if constexpr (MODE == 1) {
        u16* Cb = (u16*)Cv;                      // proj_out token-scattered
        int tok[4][4];
#pragma unroll
        for (int i = 0; i < 4; ++i)
#pragma unroll
            for (int r = 0; r < 4; ++r)
                tok[i][r] = row2tok(rowb + i * 16 + r);
#pragma unroll
        for (int j = 0; j < 4; ++j) {
            int col = n0 + wc * 64 + ((j & 1) * 16 + (j >> 1) * 32) + (lane & 15);
            float bj = bias[col];
#pragma unroll
            for (int i = 0; i < 4; ++i)
#pragma unroll
                for (int r = 0; r < 4; ++r)
                    Cb[(size_t)tok[i][r] * 256 + col] = f2bu(acc[i][j][r] + bj);
        }
    } else if constexpr (MODE == 2) {
        u16* Cb = (u16*)Cv;
#pragma unroll
        for (int j = 0; j < 4; ++j) {
            int col = n0 + wc * 64 + ((j & 1) * 16 + (j >> 1) * 32) + (lane & 15);
            float bj = bias[col];
#pragma unroll
            for (int i = 0; i < 4; ++i) {
                int rw = rowb + i * 16;
#pragma unroll
                for (int r = 0; r < 4; ++r)
                    Cb[(size_t)(rw + r) * N + col] = f2bu(fmaxf(acc[i][j][r] + bj, 0.f));
            }
        }
    } else {
        float* C = (float*)Cv;
        const u16* xr = (const u16*)extra;       // x1 bf16
#pragma unroll
        for (int j = 0; j < 4; ++j) {
            int col = n0 + wc * 64 + ((j & 1) * 16 + (j >> 1) * 32) + (lane & 15);
            float bj = bias[col], lj = extra2[col];
#pragma unroll
            for (int i = 0; i < 4; ++i) {
                int g  = grow0 + rowb + i * 16;   // g % 4 == 0, 3136 % 4 == 0:
                int b  = g / HW, hw = g - b * HW; // a 4-row pack never crosses batch
                f32x4 o;
#pragma unroll
                for (int r = 0; r < 4; ++r)
                    o[r] = bu2f(xr[(size_t)(g + r) * 256 + col]) + lj * (acc[i][j][r] + bj);
                *(f32x4*)(C + ((size_t)(b * 256 + col)) * HW + hw) = o;
            }
        }
    }
}

// ---------------- MFMA attention: one BLOCK per window, 8 waves = 8 heads -----
// The window's 49x768 bf16 qkv panel (75,264 B, CONTIGUOUS) is staged
// coalesced into LDS (rows padded to 1552 B: read bank stride 4 -> 2-way =
// free). All Q/K/V fragment reads then hit LDS instead of scattered global
// lines (the R13 latency bottleneck). Fragment math, masked softmax, Pl
// round-trip, PV, and stores identical to the verified R7-R13 kernel.
__global__ __launch_bounds__(512) void k_attn(const u16* __restrict__ qkv,
        u16* __restrict__ oattn) {
    __shared__ __align__(16) u16 QKVs[LWIN * QKVP];   // 76,048 B
    __shared__ __align__(16) u16 Pl[8][64 * 72];      // 73,728 B (tot 149,776)
    const int wv = threadIdx.x >> 6, lane = threadIdx.x & 63;
    const int win = blockIdx.x;              // 1024 = 16 batches * 64 windows
    const int head = wv, wi = win & 63;
    const int rowbase = win * LWIN;
    const int g = lane >> 4, c = lane & 15, ko = g * 8;

    // --- stage window qkv: 4704 x 16B chunks, coalesced global reads ---
    const u16* gsrc = qkv + (size_t)rowbase * 768;
    for (int idx = threadIdx.x; idx < 4704; idx += 512) {
        int row = idx / 96, chunk = idx - row * 96;
        int4 v = *(const int4*)(gsrc + (size_t)idx * 8);
        *(int4*)(QKVs + row * QKVP + chunk * 8) = v;
    }
    __syncthreads();
    const u16* qb = QKVs + head * 32;        // row pitch QKVP; K at +256, V at +512

    // --- S = Q K^T ---
    bf16x8 qf[4], kf[4];
#pragma unroll
    for (int i = 0; i < 4; ++i) {
        int r0 = i * 16 + c; if (r0 > 48) r0 = 48;   // clamp: garbage rows unused
        qf[i] = *(const bf16x8*)(qb + r0 * QKVP + ko);
        kf[i] = *(const bf16x8*)(qb + r0 * QKVP + 256 + ko);
    }
    f32x4 s[4][4] = {};
#pragma unroll
    for (int i = 0; i < 4; ++i)
#pragma unroll
        for (int j = 0; j < 4; ++j)
            s[i][j] = __builtin_amdgcn_mfma_f32_16x16x32_bf16(qf[i], kf[j], s[i][j], 0, 0, 0);

    // --- V B-fragments from LDS (k >= 49 zeroed: P tail is 0, 0*Inf = NaN) ---
    bf16x8 vb[2][2];
#pragma unroll
    for (int j2 = 0; j2 < 2; ++j2) {
        int d = j2 * 16 + c;
#pragma unroll
        for (int h = 0; h < 2; ++h)
#pragma unroll
            for (int tt = 0; tt < 8; ++tt) {
                int k = h * 32 + ko + tt;
                u16 val = (k < LWIN) ? qb[k * QKVP + 512 + d] : (u16)0;
                vb[j2][h][tt] = __builtin_bit_cast(__bf16, val);
            }
    }

    // --- masked softmax in C-layout (row = i*16+g*4+r, col = j*16+c) ---
    const int wh7 = (wi >> 3) * 7, ww7 = (wi & 7) * 7;
    int idj[4]; bool jok[4];
#pragma unroll
    for (int j = 0; j < 4; ++j) {
        int col = j * 16 + c;
        jok[j] = col < LWIN;
        int p = jok[j] ? col : 48;
        idj[j] = region_of(wh7 + p / 7) * 3 + region_of(ww7 + p % 7);
    }
#pragma unroll
    for (int i = 0; i < 4; ++i) {
#pragma unroll
        for (int r = 0; r < 4; ++r) {
            int row = i * 16 + g * 4 + r;
            int p = row < LWIN ? row : 48;
            int idi = region_of(wh7 + p / 7) * 3 + region_of(ww7 + p % 7);
            float mx = -1e30f;
#pragma unroll
            for (int j = 0; j < 4; ++j) {
                float tv = jok[j] ? fmaf(s[i][j][r], 0.17677669529663687f,
                                         (idi == idj[j]) ? 0.f : -100.f)
                                  : -1e30f;
                s[i][j][r] = tv;
                mx = fmaxf(mx, tv);
            }
            for (int o = 8; o; o >>= 1) mx = fmaxf(mx, __shfl_xor(mx, o));
            float ps = 0.f;
#pragma unroll
            for (int j = 0; j < 4; ++j) {
                float e = __expf(s[i][j][r] - mx);
                s[i][j][r] = e; ps += e;
            }
            for (int o = 8; o; o >>= 1) ps += __shfl_xor(ps, o);
            float inv = 1.f / ps;
#pragma unroll
            for (int j = 0; j < 4; ++j)
                Pl[wv][row * 72 + j * 16 + c] = f2bu(s[i][j][r] * inv);
        }
    }
    // per-wave Pl: no block barrier needed (compiler inserts lgkmcnt waits)

    // --- O = P V (M=64, N=32, K=64) ---
    f32x4 o[4][2] = {};
#pragma unroll
    for (int i = 0; i < 4; ++i) {
        bf16x8 pa0 = *(const bf16x8*)(&Pl[wv][(i * 16 + c) * 72 + ko]);
        bf16x8 pa1 = *(const bf16x8*)(&Pl[wv][(i * 16 + c) * 72 + ko + 32]);
#pragma unroll
        for (int j2 = 0; j2 < 2; ++j2) {
            o[i][j2] = __builtin_amdgcn_mfma_f32_16x16x32_bf16(pa0, vb[j2][0], o[i][j2], 0, 0, 0);
            o[i][j2] = __builtin_amdgcn_mfma_f32_16x16x32_bf16(pa1, vb[j2][1], o[i][j2], 0, 0, 0);
        }
    }
#pragma unroll
    for (int i = 0; i < 4; ++i)
#pragma unroll
        for (int r = 0; r < 4; ++r) {
            int row = i * 16 + g * 4 + r;
            if (row < LWIN) {
#pragma unroll
                for (int j2 = 0; j2 < 2; ++j2)
                    oattn[(size_t)(rowbase + row) * 256 + head * 32 + j2 * 16 + c]
                        = f2bu(o[i][j2][r]);
            }
        }
}

extern "C" void kernel_launch(void* const* d_in, const int* in_sizes, int n_in,
                              void* d_out, int out_size, void* d_ws, size_t ws_size,
                              hipStream_t stream) {
    const float* x      = (const float*)d_in[0];
    const float* ln1_g  = (const float*)d_in[1];
    const float* ln1_b  = (const float*)d_in[2];
    const float* ln2_g  = (const float*)d_in[3];
    const float* ln2_b  = (const float*)d_in[4];
    const float* qkv_w  = (const float*)d_in[5];
    const float* qkv_b  = (const float*)d_in[6];
    const float* proj_w = (const float*)d_in[7];
    const float* proj_b = (const float*)d_in[8];
    const float* ffn_w1 = (const float*)d_in[9];
    const float* ffn_b1 = (const float*)d_in[10];
    const float* ffn_w2 = (const float*)d_in[11];
    const float* ffn_b2 = (const float*)d_in[12];
    const float* lscale = (const float*)d_in[13];

    // workspace: total 104,333,312 B
    //   0        : wqt 768x256 bf16   (393,216)
    //   393216   : wpt 256x256 bf16   (131,072)
    //   524288   : w1t 1024x256 bf16  (524,288)
    //   1048576  : w2t 256x1024 bf16  (524,288)
    //   1572864  : P  25,690,112 B    hln -> o_attn -> h2 (bf16 50176x256)
    //   27262976 : Q  77,070,336 B    phase1: qkv bf16 (50176x768)
    //                                 phase2: proj_out->x1 bf16 (25,690,112)
    //                                        + f1c bf16 (51,380,224) @ +25,690,112
    char* wsb = (char*)d_ws;
    u16* wqt  = (u16*)(wsb);
    u16* wpt  = (u16*)(wsb + 393216);
    u16* w1t  = (u16*)(wsb + 524288);
    u16* w2t  = (u16*)(wsb + 1048576);
    u16* P    = (u16*)(wsb + 1572864);
    char* Qb  = wsb + 27262976;
    u16* qkvb = (u16*)Qb;
    u16* x1b  = (u16*)Qb;
    u16* f1c  = (u16*)(Qb + 25690112);

    k_wconv<<<dim3(8, 24), 256, 0, stream>>>(qkv_w, wqt, 256, 768);
    k_wconv<<<dim3(8, 8),  256, 0, stream>>>(proj_w, wpt, 256, 256);
    k_wconv<<<dim3(8, 32), 256, 0, stream>>>(ffn_w1, w1t, 256, 1024);
    k_wconv<<<dim3(32, 8), 256, 0, stream>>>(ffn_w2, w2t, 1024, 256);

    k_ln1<<<16 * 98, 256, 0, stream>>>(x, ln1_g, ln1_b, P);
    k_mgemm<0><<<dim3(196, 6), 512, 0, stream>>>(P, wqt, qkv_b, qkvb, 256, 768,
                                                 nullptr, nullptr, 0);
    k_attn<<<1024, 512, 0, stream>>>(qkvb, P);
    // proj + reverse-partition scatter -> proj_out (token-major bf16)
    k_mgemm<1><<<dim3(196, 2), 512, 0, stream>>>(P, wpt, proj_b, x1b, 256, 256,
                                                 nullptr, nullptr, 0);
    // x1 = proj_out + transpose(x) (in-place), h2 = LN2(x1) -> P
    k_ln2t<<<16 * 98, 256, 0, stream>>>(x, x1b, ln2_g, ln2_b, P);
    for (int c = 0; c < 2; ++c) {
        k_mgemm<2><<<dim3(98, 8), 512, 0, stream>>>(P + (size_t)c * FCH * 256, w1t, ffn_b1,
                                                    f1c, 256, 1024, nullptr, nullptr, 0);
        k_mgemm<3><<<dim3(98, 2), 512, 0, stream>>>(f1c, w2t, ffn_b2, d_out, 1024, 256,
                                                    x1b, lscale, c * FCH);
    }
}

// Round 15
// 272.533 us; speedup vs baseline: 1.1316x; 1.1316x over previous
//
#include <hip/hip_runtime.h>
#include <hip/hip_bf16.h>
#include <math.h>

typedef unsigned short u16;
typedef __bf16 bf16x8 __attribute__((ext_vector_type(8)));
typedef float  f32x4  __attribute__((ext_vector_type(4)));

#define DIMC 256
#define QSZ  56
#define WSZ  7
#define SSZ  3
#define LWIN 49
#define NWIN 64
#define HW   3136          // 56*56
#define NTOK 50176         // 16*3136
#define FFWD 1024
#define FCH  25088         // NTOK/2 ffn chunk rows

__device__ __forceinline__ u16 f2bu(float f) {
    __hip_bfloat16 h = __float2bfloat16(f);
    return __builtin_bit_cast(u16, h);
}
__device__ __forceinline__ float bu2f(u16 u) {
    unsigned v = (unsigned)u << 16;
    return __builtin_bit_cast(float, v);
}
__device__ __forceinline__ void gload_lds16(const void* g, void* l) {
    __builtin_amdgcn_global_load_lds((const __attribute__((address_space(1))) void*)g,
                                     (__attribute__((address_space(3))) void*)l, 16, 0, 0);
}

__device__ __forceinline__ int region_of(int h) {
    return (h < 49) ? 0 : ((h < 53) ? 1 : 2);
}

// partitioned row m = ((b*64 + wi)*49 + p) -> flat token index (with roll by -3)
__device__ __forceinline__ int row2tok(int m) {
    int b  = m / (NWIN * LWIN);
    int r  = m - b * (NWIN * LWIN);
    int wi = r / LWIN;
    int p  = r - wi * LWIN;
    int wh = wi >> 3, ww = wi & 7;
    int ph = p / 7,   pw = p - ph * 7;
    int hr = wh * 7 + ph, wr = ww * 7 + pw;
    int hs = hr + SSZ; if (hs >= QSZ) hs -= QSZ;
    int ws2 = wr + SSZ; if (ws2 >= QSZ) ws2 -= QSZ;
    return b * HW + hs * QSZ + ws2;
}

// ---------------- merged weight transpose + bf16 convert (4 weights) ----------
__device__ __forceinline__ void wconv_body(const float* __restrict__ W,
        u16* __restrict__ Wt, int K, int N, int bx, int by, int t) {
    __shared__ float tile[32][33];
    int k0 = bx * 32, n0 = by * 32;
    int tx = t & 31, ty = t >> 5;
    for (int kk = ty; kk < 32; kk += 8)
        tile[kk][tx] = W[(size_t)(k0 + kk) * N + n0 + tx];
    __syncthreads();
    for (int nn = ty; nn < 32; nn += 8)
        Wt[(size_t)(n0 + nn) * K + k0 + tx] = f2bu(tile[tx][nn]);
}

__global__ __launch_bounds__(256) void k_wconv_all(
        const float* __restrict__ qkv_w, u16* __restrict__ wqt,
        const float* __restrict__ proj_w, u16* __restrict__ wpt,
        const float* __restrict__ ffn_w1, u16* __restrict__ w1t,
        const float* __restrict__ ffn_w2, u16* __restrict__ w2t) {
    int b = blockIdx.x, t = threadIdx.x;
    if (b < 192)        wconv_body(qkv_w, wqt, 256, 768, b & 7, b >> 3, t);
    else if (b < 256) { b -= 192; wconv_body(proj_w, wpt, 256, 256,  b & 7, b >> 3, t); }
    else if (b < 512) { b -= 256; wconv_body(ffn_w1, w1t, 256, 1024, b & 7, b >> 3, t); }
    else              { b -= 512; wconv_body(ffn_w2, w2t, 1024, 256, b & 31, b >> 5, t); }
}

// ---------------- K1: BCHW -> token-major transpose + LN1 -> bf16 -------------
__global__ __launch_bounds__(256) void k_ln1(const float* __restrict__ x,
        const float* __restrict__ g, const float* __restrict__ be,
        u16* __restrict__ hln) {
    __shared__ float tile[32][257];
    __shared__ float msh[32], rsh[32];
    int blk = blockIdx.x;            // 16 * 98
    int b   = blk / 98;
    int hw0 = (blk - b * 98) * 32;
    int t   = threadIdx.x;
    int tx  = t & 31, ty = t >> 5;
    for (int c = ty; c < 256; c += 8)
        tile[tx][c] = x[(size_t)(b * 256 + c) * HW + hw0 + tx];
    __syncthreads();
    int row = t >> 3, sub = t & 7;
    float s = 0.f, sq = 0.f;
    for (int c = sub * 32; c < sub * 32 + 32; ++c) {
        float v = tile[row][c]; s += v; sq += v * v;
    }
    for (int o = 4; o; o >>= 1) { s += __shfl_down(s, o, 8); sq += __shfl_down(sq, o, 8); }
    if (sub == 0) {
        float m   = s * (1.f / 256.f);
        float var = sq * (1.f / 256.f) - m * m;
        msh[row] = m; rsh[row] = rsqrtf(var + 1e-5f);
    }
    __syncthreads();
    float gg = g[t], bb = be[t];
    for (int r2 = 0; r2 < 32; ++r2) {
        float v = tile[r2][t];
        hln[(size_t)(b * HW + hw0 + r2) * 256 + t] = f2bu((v - msh[r2]) * rsh[r2] * gg + bb);
    }
}

// ---------------- LN2 + residual: x1 = proj_out + transpose(x); h2 = LN(x1) ---
__global__ __launch_bounds__(256) void k_ln2t(const float* __restrict__ x,
        u16* __restrict__ x1b, const float* __restrict__ g,
        const float* __restrict__ be, u16* __restrict__ h2) {
    __shared__ float tile[32][257];
    __shared__ float msh[32], rsh[32];
    int blk = blockIdx.x;            // 16 * 98
    int b   = blk / 98;
    int hw0 = (blk - b * 98) * 32;
    int t   = threadIdx.x;
    int tx  = t & 31, ty = t >> 5;
    for (int c = ty; c < 256; c += 8)
        tile[tx][c] = x[(size_t)(b * 256 + c) * HW + hw0 + tx];
    __syncthreads();
    size_t base = (size_t)b * HW + hw0;
    for (int r2 = 0; r2 < 32; ++r2) {
        float v = tile[r2][t] + bu2f(x1b[(base + r2) * 256 + t]);
        tile[r2][t] = v;
        x1b[(base + r2) * 256 + t] = f2bu(v);
    }
    __syncthreads();
    int row = t >> 3, sub = t & 7;
    float s = 0.f, sq = 0.f;
    for (int c = sub * 32; c < sub * 32 + 32; ++c) {
        float v = tile[row][c]; s += v; sq += v * v;
    }
    for (int o = 4; o; o >>= 1) { s += __shfl_down(s, o, 8); sq += __shfl_down(sq, o, 8); }
    if (sub == 0) {
        float m   = s * (1.f / 256.f);
        float var = sq * (1.f / 256.f) - m * m;
        msh[row] = m; rsh[row] = rsqrtf(var + 1e-5f);
    }
    __syncthreads();
    float gg = g[t], bb = be[t];
    for (int r2 = 0; r2 < 32; ++r2) {
        float v = tile[r2][t];
        h2[(base + r2) * 256 + t] = f2bu((v - msh[r2]) * rsh[r2] * gg + bb);
    }
}

// ---------------- MFMA GEMM, 256x128 tile, 512 thr (qkv / ffn1) ---------------
// R13-verified: 2-buffer depth-1 (barriers A+B, vmcnt(3)), T2 swizzle
// (conflicts = 0). MODE 0: qkv -> bf16 +bias (N=768, A gathered via row2tok);
// MODE 2: ffn1 -> bf16 relu (N=1024).
template<int MODE>
__global__ __launch_bounds__(512) void k_mgemm256(
        const u16* __restrict__ A, const u16* __restrict__ Bt,
        const float* __restrict__ bias, void* __restrict__ Cv, int K, int N) {
    __shared__ __align__(16) u16 As[2][256 * 32];
    __shared__ __align__(16) u16 Bs[2][128 * 32];
    const int m0 = blockIdx.x * 256, n0 = blockIdx.y * 128;
    const int t = threadIdx.x, lane = t & 63;
    const int wv = t >> 6, wr = wv >> 1, wc = wv & 1;

    const int kc = (t & 3) ^ ((t >> 3) & 3);
    int ar0 = m0 + (t >> 2), ar1 = m0 + 128 + (t >> 2);
    if (MODE == 0) { ar0 = row2tok(ar0); ar1 = row2tok(ar1); }
    const u16* gA0 = A  + (size_t)ar0 * K + kc * 8;
    const u16* gA1 = A  + (size_t)ar1 * K + kc * 8;
    const u16* gB0 = Bt + (size_t)(n0 + (t >> 2)) * K + kc * 8;

    f32x4 acc[4][4] = {};
    const int ra = wr * 64 + (lane & 15);
    const int rb = wc * 64 + (lane & 15);
    const int kos = (((lane >> 4) ^ (lane >> 1)) & 3) * 8;
    const int nIter = K >> 5;

    gload_lds16(gA0, As[0] + t * 8);
    gload_lds16(gA1, As[0] + 4096 + t * 8);
    gload_lds16(gB0, Bs[0] + t * 8);

    int cur = 0;
    for (int it = 0; it < nIter; ++it) {
        if (it + 1 < nIter) {
            const int k1 = (it + 1) << 5;
            gload_lds16(gA0 + k1, As[cur ^ 1] + t * 8);
            gload_lds16(gA1 + k1, As[cur ^ 1] + 4096 + t * 8);
            gload_lds16(gB0 + k1, Bs[cur ^ 1] + t * 8);
            asm volatile("s_waitcnt vmcnt(3)" ::: "memory");
        } else {
            asm volatile("s_waitcnt vmcnt(0)" ::: "memory");
        }
        __builtin_amdgcn_s_barrier();
        __builtin_amdgcn_sched_barrier(0);
        bf16x8 af[4], bfr[4];
#pragma unroll
        for (int i = 0; i < 4; ++i)
            af[i] = *(const bf16x8*)(As[cur] + (ra + i * 16) * 32 + kos);
#pragma unroll
        for (int j = 0; j < 4; ++j)
            bfr[j] = *(const bf16x8*)(Bs[cur] + (rb + ((j & 1) * 16 + (j >> 1) * 32)) * 32 + kos);
        asm volatile("s_waitcnt lgkmcnt(0)" ::: "memory");
        __builtin_amdgcn_sched_barrier(0);
        __builtin_amdgcn_s_barrier();
#pragma unroll
        for (int i = 0; i < 4; ++i)
#pragma unroll
            for (int j = 0; j < 4; ++j)
                acc[i][j] = __builtin_amdgcn_mfma_f32_16x16x32_bf16(af[i], bfr[j], acc[i][j], 0, 0, 0);
        cur ^= 1;
    }

    const int rowb = m0 + wr * 64 + ((lane >> 4) * 4);
    u16* Cb = (u16*)Cv;
#pragma unroll
    for (int j = 0; j < 4; ++j) {
        int col = n0 + wc * 64 + ((j & 1) * 16 + (j >> 1) * 32) + (lane & 15);
        float bj = bias[col];
#pragma unroll
        for (int i = 0; i < 4; ++i) {
            int rw = rowb + i * 16;
#pragma unroll
            for (int r = 0; r < 4; ++r) {
                float v = acc[i][j][r] + bj;
                if (MODE == 2) v = fmaxf(v, 0.f);
                Cb[(size_t)(rw + r) * N + col] = f2bu(v);
            }
        }
    }
}

// ---------------- MFMA GEMM, 128x128 tile, 256 thr (proj / ffn2) --------------
// R10-verified 2-buffer loop + T2 swizzle. 784/392-block grids keep CUs full.
// MODE 1: proj -> bf16 proj_out scattered rows (row2tok)+bias  (N=256)
// MODE 3: ffn2 -> fp32 BCHW d_out = x1(bf16) + ls*(acc+bias)   (N=256)
template<int MODE>
__global__ __launch_bounds__(256) void k_mgemm128(
        const u16* __restrict__ A, const u16* __restrict__ Bt,
        const float* __restrict__ bias, void* __restrict__ Cv,
        int K, int N, const void* __restrict__ extra,
        const float* __restrict__ extra2, int grow0) {
    __shared__ __align__(16) u16 As[2][128 * 32];
    __shared__ __align__(16) u16 Bs[2][128 * 32];
    const int m0 = blockIdx.x * 128, n0 = blockIdx.y * 128;
    const int t = threadIdx.x, lane = t & 63;
    const int wv = t >> 6, wr = wv >> 1, wc = wv & 1;

    const int kc = (t & 3) ^ ((t >> 3) & 3);
    const u16* gA0 = A  + (size_t)(m0 + (t >> 2)) * K + kc * 8;
    const u16* gA1 = A  + (size_t)(m0 + 64 + (t >> 2)) * K + kc * 8;
    const u16* gB0 = Bt + (size_t)(n0 + (t >> 2)) * K + kc * 8;
    const u16* gB1 = Bt + (size_t)(n0 + 64 + (t >> 2)) * K + kc * 8;

    f32x4 acc[4][4] = {};
    const int ra = wr * 64 + (lane & 15);
    const int rb = wc * 64 + (lane & 15);
    const int kos = (((lane >> 4) ^ (lane >> 1)) & 3) * 8;
    const int nIter = K >> 5;

    gload_lds16(gA0, As[0] + t * 8);
    gload_lds16(gA1, As[0] + 2048 + t * 8);
    gload_lds16(gB0, Bs[0] + t * 8);
    gload_lds16(gB1, Bs[0] + 2048 + t * 8);

    int cur = 0;
    for (int it = 0; it < nIter; ++it) {
        if (it + 1 < nIter) {
            const int k1 = (it + 1) << 5;
            gload_lds16(gA0 + k1, As[cur ^ 1] + t * 8);
            gload_lds16(gA1 + k1, As[cur ^ 1] + 2048 + t * 8);
            gload_lds16(gB0 + k1, Bs[cur ^ 1] + t * 8);
            gload_lds16(gB1 + k1, Bs[cur ^ 1] + 2048 + t * 8);
            asm volatile("s_waitcnt vmcnt(4)" ::: "memory");
        } else {
            asm volatile("s_waitcnt vmcnt(0)" ::: "memory");
        }
        __builtin_amdgcn_s_barrier();
        __builtin_amdgcn_sched_barrier(0);
        bf16x8 af[4], bfr[4];
#pragma unroll
        for (int i = 0; i < 4; ++i)
            af[i] = *(const bf16x8*)(As[cur] + (ra + i * 16) * 32 + kos);
#pragma unroll
        for (int j = 0; j < 4; ++j)
            bfr[j] = *(const bf16x8*)(Bs[cur] + (rb + j * 16) * 32 + kos);
        asm volatile("s_waitcnt lgkmcnt(0)" ::: "memory");
        __builtin_amdgcn_sched_barrier(0);
        __builtin_amdgcn_s_barrier();
#pragma unroll
        for (int i = 0; i < 4; ++i)
#pragma unroll
            for (int j = 0; j < 4; ++j)
                acc[i][j] = __builtin_amdgcn_mfma_f32_16x16x32_bf16(af[i], bfr[j], acc[i][j], 0, 0, 0);
        cur ^= 1;
    }

    const int colb = n0 + wc * 64 + (lane & 15);
    const int rowb = m0 + wr * 64 + ((lane >> 4) * 4);

    if constexpr (MODE == 1) {
        u16* Cb = (u16*)Cv;
        int tok[4][4];
#pragma unroll
        for (int i = 0; i < 4; ++i)
#pragma unroll
            for (int r = 0; r < 4; ++r)
                tok[i][r] = row2tok(rowb + i * 16 + r);
#pragma unroll
        for (int j = 0; j < 4; ++j) {
            int col = colb + j * 16; float bj = bias[col];
#pragma unroll
            for (int i = 0; i < 4; ++i)
#pragma unroll
                for (int r = 0; r < 4; ++r)
                    Cb[(size_t)tok[i][r] * 256 + col] = f2bu(acc[i][j][r] + bj);
        }
    } else {
        float* C = (float*)Cv;
        const u16* xr = (const u16*)extra;       // x1 bf16
#pragma unroll
        for (int j = 0; j < 4; ++j) {
            int col = colb + j * 16;
            float bj = bias[col], lj = extra2[col];
#pragma unroll
            for (int i = 0; i < 4; ++i) {
                int g  = grow0 + rowb + i * 16;   // 4-row pack never crosses batch
                int b  = g / HW, hw = g - b * HW;
                f32x4 o;
#pragma unroll
                for (int r = 0; r < 4; ++r)
                    o[r] = bu2f(xr[(size_t)(g + r) * 256 + col]) + lj * (acc[i][j][r] + bj);
                *(f32x4*)(C + ((size_t)(b * 256 + col)) * HW + hw) = o;
            }
        }
    }
}

// ---------------- MFMA attention: one wave per (window, head) -----------------
// R13 structure + 3 deltas: (1) Pl shrunk to 49 rows/wave + shared tail pad
// (30.4 KB -> 5 blocks/CU; PV reads past row 48 hit neighbor/tail garbage that
// feeds only DISCARDED output rows — MFMA A-row locality makes this safe);
// (2) Pl writes gated to row<49 (required for the overlap); (3) vb loads
// hoisted before QK^T; setprio(1) around both MFMA clusters (T5, m191).
__global__ __launch_bounds__(256, 4) void k_attn(const u16* __restrict__ qkv,
        u16* __restrict__ oattn) {
    __shared__ __align__(16) u16 Pl[4 * 49 * 72 + 15 * 72];   // 30,384 B
    const int wv = threadIdx.x >> 6, lane = threadIdx.x & 63;
    const int task = blockIdx.x * 4 + wv;    // 8192 = 1024 win * 8 heads
    const int head = task & 7, win = task >> 3, wi = win & 63;
    const int rowbase = win * LWIN;
    const int g = lane >> 4, c = lane & 15, ko = g * 8;
    const u16* qb = qkv + (size_t)rowbase * 768 + head * 32;
    u16* pl = Pl + wv * (49 * 72);

    // --- V B-fragments direct to registers, hoisted (k >= 49 zeroed) ---
    bf16x8 vb[2][2];
#pragma unroll
    for (int j2 = 0; j2 < 2; ++j2) {
        int d = j2 * 16 + c;
#pragma unroll
        for (int h = 0; h < 2; ++h)
#pragma unroll
            for (int tt = 0; tt < 8; ++tt) {
                int k = h * 32 + ko + tt;
                u16 val = (k < LWIN) ? qb[(size_t)k * 768 + 512 + d] : (u16)0;
                vb[j2][h][tt] = __builtin_bit_cast(__bf16, val);
            }
    }

    // --- S = Q K^T ---
    bf16x8 qf[4], kf[4];
#pragma unroll
    for (int i = 0; i < 4; ++i) {
        int r0 = i * 16 + c; if (r0 > 48) r0 = 48;   // clamp: garbage rows unused
        qf[i] = *(const bf16x8*)(qb + (size_t)r0 * 768 + ko);
        kf[i] = *(const bf16x8*)(qb + (size_t)r0 * 768 + 256 + ko);
    }
    f32x4 s[4][4] = {};
    __builtin_amdgcn_s_setprio(1);
#pragma unroll
    for (int i = 0; i < 4; ++i)
#pragma unroll
        for (int j = 0; j < 4; ++j)
            s[i][j] = __builtin_amdgcn_mfma_f32_16x16x32_bf16(qf[i], kf[j], s[i][j], 0, 0, 0);
    __builtin_amdgcn_s_setprio(0);

    // --- masked softmax in C-layout (row = i*16+g*4+r, col = j*16+c) ---
    const int wh7 = (wi >> 3) * 7, ww7 = (wi & 7) * 7;
    int idj[4]; bool jok[4];
#pragma unroll
    for (int j = 0; j < 4; ++j) {
        int col = j * 16 + c;
        jok[j] = col < LWIN;
        int p = jok[j] ? col : 48;
        idj[j] = region_of(wh7 + p / 7) * 3 + region_of(ww7 + p % 7);
    }
#pragma unroll
    for (int i = 0; i < 4; ++i) {
#pragma unroll
        for (int r = 0; r < 4; ++r) {
            int row = i * 16 + g * 4 + r;
            int p = row < LWIN ? row : 48;
            int idi = region_of(wh7 + p / 7) * 3 + region_of(ww7 + p % 7);
            float mx = -1e30f;
#pragma unroll
            for (int j = 0; j < 4; ++j) {
                float tv = jok[j] ? fmaf(s[i][j][r], 0.17677669529663687f,
                                         (idi == idj[j]) ? 0.f : -100.f)
                                  : -1e30f;
                s[i][j][r] = tv;
                mx = fmaxf(mx, tv);
            }
            for (int o = 8; o; o >>= 1) mx = fmaxf(mx, __shfl_xor(mx, o));
            float ps = 0.f;
#pragma unroll
            for (int j = 0; j < 4; ++j) {
                float e = __expf(s[i][j][r] - mx);
                s[i][j][r] = e; ps += e;
            }
            for (int o = 8; o; o >>= 1) ps += __shfl_xor(ps, o);
            float inv = 1.f / ps;
            if (row < LWIN) {
#pragma unroll
                for (int j = 0; j < 4; ++j)
                    pl[row * 72 + j * 16 + c] = f2bu(s[i][j][r] * inv);
            }
        }
    }
    // per-wave pl: no block barrier needed (compiler inserts lgkmcnt waits)

    // --- O = P V (M=64, N=32, K=64) ---
    f32x4 o[4][2] = {};
    __builtin_amdgcn_s_setprio(1);
#pragma unroll
    for (int i = 0; i < 4; ++i) {
        bf16x8 pa0 = *(const bf16x8*)(&pl[(i * 16 + c) * 72 + ko]);
        bf16x8 pa1 = *(const bf16x8*)(&pl[(i * 16 + c) * 72 + ko + 32]);
#pragma unroll
        for (int j2 = 0; j2 < 2; ++j2) {
            o[i][j2] = __builtin_amdgcn_mfma_f32_16x16x32_bf16(pa0, vb[j2][0], o[i][j2], 0, 0, 0);
            o[i][j2] = __builtin_amdgcn_mfma_f32_16x16x32_bf16(pa1, vb[j2][1], o[i][j2], 0, 0, 0);
        }
    }
    __builtin_amdgcn_s_setprio(0);
#pragma unroll
    for (int i = 0; i < 4; ++i)
#pragma unroll
        for (int r = 0; r < 4; ++r) {
            int row = i * 16 + g * 4 + r;
            if (row < LWIN) {
#pragma unroll
                for (int j2 = 0; j2 < 2; ++j2)
                    oattn[(size_t)(rowbase + row) * 256 + head * 32 + j2 * 16 + c]
                        = f2bu(o[i][j2][r]);
            }
        }
}

extern "C" void kernel_launch(void* const* d_in, const int* in_sizes, int n_in,
                              void* d_out, int out_size, void* d_ws, size_t ws_size,
                              hipStream_t stream) {
    const float* x      = (const float*)d_in[0];
    const float* ln1_g  = (const float*)d_in[1];
    const float* ln1_b  = (const float*)d_in[2];
    const float* ln2_g  = (const float*)d_in[3];
    const float* ln2_b  = (const float*)d_in[4];
    const float* qkv_w  = (const float*)d_in[5];
    const float* qkv_b  = (const float*)d_in[6];
    const float* proj_w = (const float*)d_in[7];
    const float* proj_b = (const float*)d_in[8];
    const float* ffn_w1 = (const float*)d_in[9];
    const float* ffn_b1 = (const float*)d_in[10];
    const float* ffn_w2 = (const float*)d_in[11];
    const float* ffn_b2 = (const float*)d_in[12];
    const float* lscale = (const float*)d_in[13];

    // workspace: total 104,333,312 B (layout unchanged since R6)
    char* wsb = (char*)d_ws;
    u16* wqt  = (u16*)(wsb);
    u16* wpt  = (u16*)(wsb + 393216);
    u16* w1t  = (u16*)(wsb + 524288);
    u16* w2t  = (u16*)(wsb + 1048576);
    u16* P    = (u16*)(wsb + 1572864);
    char* Qb  = wsb + 27262976;
    u16* qkvb = (u16*)Qb;
    u16* x1b  = (u16*)Qb;
    u16* f1c  = (u16*)(Qb + 25690112);

    k_wconv_all<<<768, 256, 0, stream>>>(qkv_w, wqt, proj_w, wpt, ffn_w1, w1t, ffn_w2, w2t);

    k_ln1<<<16 * 98, 256, 0, stream>>>(x, ln1_g, ln1_b, P);
    k_mgemm256<0><<<dim3(196, 6), 512, 0, stream>>>(P, wqt, qkv_b, qkvb, 256, 768);
    k_attn<<<2048, 256, 0, stream>>>(qkvb, P);
    // proj + reverse-partition scatter -> proj_out (token-major bf16)
    k_mgemm128<1><<<dim3(392, 2), 256, 0, stream>>>(P, wpt, proj_b, x1b, 256, 256,
                                                    nullptr, nullptr, 0);
    // x1 = proj_out + transpose(x) (in-place), h2 = LN2(x1) -> P
    k_ln2t<<<16 * 98, 256, 0, stream>>>(x, x1b, ln2_g, ln2_b, P);
    for (int c = 0; c < 2; ++c) {
        k_mgemm256<2><<<dim3(98, 8), 512, 0, stream>>>(P + (size_t)c * FCH * 256, w1t, ffn_b1,
                                                       f1c, 256, 1024);
        k_mgemm128<3><<<dim3(196, 2), 256, 0, stream>>>(f1c, w2t, ffn_b2, d_out, 1024, 256,
                                                        x1b, lscale, c * FCH);
    }
}

// Round 16
// 269.702 us; speedup vs baseline: 1.1435x; 1.0105x over previous
//
#include <hip/hip_runtime.h>
#include <hip/hip_bf16.h>
#include <math.h>

typedef unsigned short u16;
typedef __bf16 bf16x8 __attribute__((ext_vector_type(8)));
typedef float  f32x4  __attribute__((ext_vector_type(4)));

#define DIMC 256
#define QSZ  56
#define WSZ  7
#define SSZ  3
#define LWIN 49
#define NWIN 64
#define HW   3136          // 56*56
#define NTOK 50176         // 16*3136
#define FFWD 1024
#define FCH  25088         // NTOK/2 ffn chunk rows

__device__ __forceinline__ u16 f2bu(float f) {
    __hip_bfloat16 h = __float2bfloat16(f);
    return __builtin_bit_cast(u16, h);
}
__device__ __forceinline__ float bu2f(u16 u) {
    unsigned v = (unsigned)u << 16;
    return __builtin_bit_cast(float, v);
}
__device__ __forceinline__ void gload_lds16(const void* g, void* l) {
    __builtin_amdgcn_global_load_lds((const __attribute__((address_space(1))) void*)g,
                                     (__attribute__((address_space(3))) void*)l, 16, 0, 0);
}

__device__ __forceinline__ int region_of(int h) {
    return (h < 49) ? 0 : ((h < 53) ? 1 : 2);
}

// partitioned row m = ((b*64 + wi)*49 + p) -> flat token index (with roll by -3)
__device__ __forceinline__ int row2tok(int m) {
    int b  = m / (NWIN * LWIN);
    int r  = m - b * (NWIN * LWIN);
    int wi = r / LWIN;
    int p  = r - wi * LWIN;
    int wh = wi >> 3, ww = wi & 7;
    int ph = p / 7,   pw = p - ph * 7;
    int hr = wh * 7 + ph, wr = ww * 7 + pw;
    int hs = hr + SSZ; if (hs >= QSZ) hs -= QSZ;
    int ws2 = wr + SSZ; if (ws2 >= QSZ) ws2 -= QSZ;
    return b * HW + hs * QSZ + ws2;
}

// ---------------- merged weight transpose + bf16 convert (4 weights) ----------
__device__ __forceinline__ void wconv_body(const float* __restrict__ W,
        u16* __restrict__ Wt, int K, int N, int bx, int by, int t) {
    __shared__ float tile[32][33];
    int k0 = bx * 32, n0 = by * 32;
    int tx = t & 31, ty = t >> 5;
    for (int kk = ty; kk < 32; kk += 8)
        tile[kk][tx] = W[(size_t)(k0 + kk) * N + n0 + tx];
    __syncthreads();
    for (int nn = ty; nn < 32; nn += 8)
        Wt[(size_t)(n0 + nn) * K + k0 + tx] = f2bu(tile[tx][nn]);
}

__global__ __launch_bounds__(256) void k_wconv_all(
        const float* __restrict__ qkv_w, u16* __restrict__ wqt,
        const float* __restrict__ proj_w, u16* __restrict__ wpt,
        const float* __restrict__ ffn_w1, u16* __restrict__ w1t,
        const float* __restrict__ ffn_w2, u16* __restrict__ w2t) {
    int b = blockIdx.x, t = threadIdx.x;
    if (b < 192)        wconv_body(qkv_w, wqt, 256, 768, b & 7, b >> 3, t);
    else if (b < 256) { b -= 192; wconv_body(proj_w, wpt, 256, 256,  b & 7, b >> 3, t); }
    else if (b < 512) { b -= 256; wconv_body(ffn_w1, w1t, 256, 1024, b & 7, b >> 3, t); }
    else              { b -= 512; wconv_body(ffn_w2, w2t, 1024, 256, b & 31, b >> 5, t); }
}

// ---------------- K1: BCHW -> token-major transpose + LN1 -> bf16 -------------
__global__ __launch_bounds__(256) void k_ln1(const float* __restrict__ x,
        const float* __restrict__ g, const float* __restrict__ be,
        u16* __restrict__ hln) {
    __shared__ float tile[32][257];
    __shared__ float msh[32], rsh[32];
    int blk = blockIdx.x;            // 16 * 98
    int b   = blk / 98;
    int hw0 = (blk - b * 98) * 32;
    int t   = threadIdx.x;
    int tx  = t & 31, ty = t >> 5;
    for (int c = ty; c < 256; c += 8)
        tile[tx][c] = x[(size_t)(b * 256 + c) * HW + hw0 + tx];
    __syncthreads();
    int row = t >> 3, sub = t & 7;
    float s = 0.f, sq = 0.f;
    for (int c = sub * 32; c < sub * 32 + 32; ++c) {
        float v = tile[row][c]; s += v; sq += v * v;
    }
    for (int o = 4; o; o >>= 1) { s += __shfl_down(s, o, 8); sq += __shfl_down(sq, o, 8); }
    if (sub == 0) {
        float m   = s * (1.f / 256.f);
        float var = sq * (1.f / 256.f) - m * m;
        msh[row] = m; rsh[row] = rsqrtf(var + 1e-5f);
    }
    __syncthreads();
    float gg = g[t], bb = be[t];
    for (int r2 = 0; r2 < 32; ++r2) {
        float v = tile[r2][t];
        hln[(size_t)(b * HW + hw0 + r2) * 256 + t] = f2bu((v - msh[r2]) * rsh[r2] * gg + bb);
    }
}

// ---------------- LN2 + residual: x1 = proj_out + transpose(x); h2 = LN(x1) ---
__global__ __launch_bounds__(256) void k_ln2t(const float* __restrict__ x,
        u16* __restrict__ x1b, const float* __restrict__ g,
        const float* __restrict__ be, u16* __restrict__ h2) {
    __shared__ float tile[32][257];
    __shared__ float msh[32], rsh[32];
    int blk = blockIdx.x;            // 16 * 98
    int b   = blk / 98;
    int hw0 = (blk - b * 98) * 32;
    int t   = threadIdx.x;
    int tx  = t & 31, ty = t >> 5;
    for (int c = ty; c < 256; c += 8)
        tile[tx][c] = x[(size_t)(b * 256 + c) * HW + hw0 + tx];
    __syncthreads();
    size_t base = (size_t)b * HW + hw0;
    for (int r2 = 0; r2 < 32; ++r2) {
        float v = tile[r2][t] + bu2f(x1b[(base + r2) * 256 + t]);
        tile[r2][t] = v;
        x1b[(base + r2) * 256 + t] = f2bu(v);
    }
    __syncthreads();
    int row = t >> 3, sub = t & 7;
    float s = 0.f, sq = 0.f;
    for (int c = sub * 32; c < sub * 32 + 32; ++c) {
        float v = tile[row][c]; s += v; sq += v * v;
    }
    for (int o = 4; o; o >>= 1) { s += __shfl_down(s, o, 8); sq += __shfl_down(sq, o, 8); }
    if (sub == 0) {
        float m   = s * (1.f / 256.f);
        float var = sq * (1.f / 256.f) - m * m;
        msh[row] = m; rsh[row] = rsqrtf(var + 1e-5f);
    }
    __syncthreads();
    float gg = g[t], bb = be[t];
    for (int r2 = 0; r2 < 32; ++r2) {
        float v = tile[r2][t];
        h2[(base + r2) * 256 + t] = f2bu((v - msh[r2]) * rsh[r2] * gg + bb);
    }
}

// ---------------- MFMA GEMM, 256x128 tile, 512 thr (qkv / ffn1) ---------------
// R13-verified: 2-buffer depth-1 (barriers A+B, vmcnt(3)), T2 swizzle
// (conflicts = 0). MODE 0: qkv -> bf16 +bias (N=768, A gathered via row2tok);
// MODE 2: ffn1 -> bf16 relu (N=1024).
template<int MODE>
__global__ __launch_bounds__(512) void k_mgemm256(
        const u16* __restrict__ A, const u16* __restrict__ Bt,
        const float* __restrict__ bias, void* __restrict__ Cv, int K, int N) {
    __shared__ __align__(16) u16 As[2][256 * 32];
    __shared__ __align__(16) u16 Bs[2][128 * 32];
    const int m0 = blockIdx.x * 256, n0 = blockIdx.y * 128;
    const int t = threadIdx.x, lane = t & 63;
    const int wv = t >> 6, wr = wv >> 1, wc = wv & 1;

    const int kc = (t & 3) ^ ((t >> 3) & 3);
    int ar0 = m0 + (t >> 2), ar1 = m0 + 128 + (t >> 2);
    if (MODE == 0) { ar0 = row2tok(ar0); ar1 = row2tok(ar1); }
    const u16* gA0 = A  + (size_t)ar0 * K + kc * 8;
    const u16* gA1 = A  + (size_t)ar1 * K + kc * 8;
    const u16* gB0 = Bt + (size_t)(n0 + (t >> 2)) * K + kc * 8;

    f32x4 acc[4][4] = {};
    const int ra = wr * 64 + (lane & 15);
    const int rb = wc * 64 + (lane & 15);
    const int kos = (((lane >> 4) ^ (lane >> 1)) & 3) * 8;
    const int nIter = K >> 5;

    gload_lds16(gA0, As[0] + t * 8);
    gload_lds16(gA1, As[0] + 4096 + t * 8);
    gload_lds16(gB0, Bs[0] + t * 8);

    int cur = 0;
    for (int it = 0; it < nIter; ++it) {
        if (it + 1 < nIter) {
            const int k1 = (it + 1) << 5;
            gload_lds16(gA0 + k1, As[cur ^ 1] + t * 8);
            gload_lds16(gA1 + k1, As[cur ^ 1] + 4096 + t * 8);
            gload_lds16(gB0 + k1, Bs[cur ^ 1] + t * 8);
            asm volatile("s_waitcnt vmcnt(3)" ::: "memory");
        } else {
            asm volatile("s_waitcnt vmcnt(0)" ::: "memory");
        }
        __builtin_amdgcn_s_barrier();
        __builtin_amdgcn_sched_barrier(0);
        bf16x8 af[4], bfr[4];
#pragma unroll
        for (int i = 0; i < 4; ++i)
            af[i] = *(const bf16x8*)(As[cur] + (ra + i * 16) * 32 + kos);
#pragma unroll
        for (int j = 0; j < 4; ++j)
            bfr[j] = *(const bf16x8*)(Bs[cur] + (rb + ((j & 1) * 16 + (j >> 1) * 32)) * 32 + kos);
        asm volatile("s_waitcnt lgkmcnt(0)" ::: "memory");
        __builtin_amdgcn_sched_barrier(0);
        __builtin_amdgcn_s_barrier();
#pragma unroll
        for (int i = 0; i < 4; ++i)
#pragma unroll
            for (int j = 0; j < 4; ++j)
                acc[i][j] = __builtin_amdgcn_mfma_f32_16x16x32_bf16(af[i], bfr[j], acc[i][j], 0, 0, 0);
        cur ^= 1;
    }

    const int rowb = m0 + wr * 64 + ((lane >> 4) * 4);
    u16* Cb = (u16*)Cv;
#pragma unroll
    for (int j = 0; j < 4; ++j) {
        int col = n0 + wc * 64 + ((j & 1) * 16 + (j >> 1) * 32) + (lane & 15);
        float bj = bias[col];
#pragma unroll
        for (int i = 0; i < 4; ++i) {
            int rw = rowb + i * 16;
#pragma unroll
            for (int r = 0; r < 4; ++r) {
                float v = acc[i][j][r] + bj;
                if (MODE == 2) v = fmaxf(v, 0.f);
                Cb[(size_t)(rw + r) * N + col] = f2bu(v);
            }
        }
    }
}

// ---------------- MFMA GEMM, 128x128 tile, 256 thr (ffn2) ---------------------
// R10-verified 2-buffer loop + T2 swizzle.
// MODE 3: ffn2 -> fp32 BCHW d_out = x1(bf16) + ls*(acc+bias)   (N=256)
template<int MODE>
__global__ __launch_bounds__(256) void k_mgemm128(
        const u16* __restrict__ A, const u16* __restrict__ Bt,
        const float* __restrict__ bias, void* __restrict__ Cv,
        int K, int N, const void* __restrict__ extra,
        const float* __restrict__ extra2, int grow0) {
    __shared__ __align__(16) u16 As[2][128 * 32];
    __shared__ __align__(16) u16 Bs[2][128 * 32];
    const int m0 = blockIdx.x * 128, n0 = blockIdx.y * 128;
    const int t = threadIdx.x, lane = t & 63;
    const int wv = t >> 6, wr = wv >> 1, wc = wv & 1;

    const int kc = (t & 3) ^ ((t >> 3) & 3);
    const u16* gA0 = A  + (size_t)(m0 + (t >> 2)) * K + kc * 8;
    const u16* gA1 = A  + (size_t)(m0 + 64 + (t >> 2)) * K + kc * 8;
    const u16* gB0 = Bt + (size_t)(n0 + (t >> 2)) * K + kc * 8;
    const u16* gB1 = Bt + (size_t)(n0 + 64 + (t >> 2)) * K + kc * 8;

    f32x4 acc[4][4] = {};
    const int ra = wr * 64 + (lane & 15);
    const int rb = wc * 64 + (lane & 15);
    const int kos = (((lane >> 4) ^ (lane >> 1)) & 3) * 8;
    const int nIter = K >> 5;

    gload_lds16(gA0, As[0] + t * 8);
    gload_lds16(gA1, As[0] + 2048 + t * 8);
    gload_lds16(gB0, Bs[0] + t * 8);
    gload_lds16(gB1, Bs[0] + 2048 + t * 8);

    int cur = 0;
    for (int it = 0; it < nIter; ++it) {
        if (it + 1 < nIter) {
            const int k1 = (it + 1) << 5;
            gload_lds16(gA0 + k1, As[cur ^ 1] + t * 8);
            gload_lds16(gA1 + k1, As[cur ^ 1] + 2048 + t * 8);
            gload_lds16(gB0 + k1, Bs[cur ^ 1] + t * 8);
            gload_lds16(gB1 + k1, Bs[cur ^ 1] + 2048 + t * 8);
            asm volatile("s_waitcnt vmcnt(4)" ::: "memory");
        } else {
            asm volatile("s_waitcnt vmcnt(0)" ::: "memory");
        }
        __builtin_amdgcn_s_barrier();
        __builtin_amdgcn_sched_barrier(0);
        bf16x8 af[4], bfr[4];
#pragma unroll
        for (int i = 0; i < 4; ++i)
            af[i] = *(const bf16x8*)(As[cur] + (ra + i * 16) * 32 + kos);
#pragma unroll
        for (int j = 0; j < 4; ++j)
            bfr[j] = *(const bf16x8*)(Bs[cur] + (rb + j * 16) * 32 + kos);
        asm volatile("s_waitcnt lgkmcnt(0)" ::: "memory");
        __builtin_amdgcn_sched_barrier(0);
        __builtin_amdgcn_s_barrier();
#pragma unroll
        for (int i = 0; i < 4; ++i)
#pragma unroll
            for (int j = 0; j < 4; ++j)
                acc[i][j] = __builtin_amdgcn_mfma_f32_16x16x32_bf16(af[i], bfr[j], acc[i][j], 0, 0, 0);
        cur ^= 1;
    }

    const int colb = n0 + wc * 64 + (lane & 15);
    const int rowb = m0 + wr * 64 + ((lane >> 4) * 4);

    float* C = (float*)Cv;
    const u16* xr = (const u16*)extra;       // x1 bf16
#pragma unroll
    for (int j = 0; j < 4; ++j) {
        int col = colb + j * 16;
        float bj = bias[col], lj = extra2[col];
#pragma unroll
        for (int i = 0; i < 4; ++i) {
            int g  = grow0 + rowb + i * 16;   // 4-row pack never crosses batch
            int b  = g / HW, hw = g - b * HW;
            f32x4 o;
#pragma unroll
            for (int r = 0; r < 4; ++r)
                o[r] = bu2f(xr[(size_t)(g + r) * 256 + col]) + lj * (acc[i][j][r] + bj);
            *(f32x4*)(C + ((size_t)(b * 256 + col)) * HW + hw) = o;
        }
    }
}

// ---------------- fused attention + proj: one BLOCK per window ----------------
// 8 waves = 8 heads. Attention phase is byte-identical to the R15-verified
// k_attn (vb hoist, clamp reads, in-register masked softmax, per-wave Pl,
// rows>=49 discarded, setprio around MFMA clusters). Then the block's full
// 49x256 attention output goes to a padded LDS tile (stride 264 u16 -> 2-way
// banks = free) and proj (256x256, K=256) runs in-block with the verified
// swizzled weight staging; epilogue scatters to x1b via row2tok (+proj bias).
// LDS union: phase A = 8 Pl regions (+tail pad, 58.6 KB within 66.6 KB);
// phase B = o_t (33792 B) + wstage (32768 B) = 66560 B. Total 66,560 B ->
// 2 blocks/CU. Barriers separate the phases (Pl consumed before overwrite).
__global__ __launch_bounds__(512) void k_attnproj(const u16* __restrict__ qkv,
        const u16* __restrict__ wpt, const float* __restrict__ pbias,
        u16* __restrict__ x1b) {
    __shared__ __align__(16) u16 U[33280];
    const int wv = threadIdx.x >> 6, lane = threadIdx.x & 63;
    const int win = blockIdx.x, head = wv, wi = win & 63;
    const int rowbase = win * LWIN;
    const int g = lane >> 4, c = lane & 15, ko = g * 8;
    const u16* qb = qkv + (size_t)rowbase * 768 + head * 32;
    u16* pl = U + wv * (LWIN * 72);

    // --- V B-fragments direct to registers, hoisted (k >= 49 zeroed) ---
    bf16x8 vb[2][2];
#pragma unroll
    for (int j2 = 0; j2 < 2; ++j2) {
        int d = j2 * 16 + c;
#pragma unroll
        for (int h = 0; h < 2; ++h)
#pragma unroll
            for (int tt = 0; tt < 8; ++tt) {
                int k = h * 32 + ko + tt;
                u16 val = (k < LWIN) ? qb[(size_t)k * 768 + 512 + d] : (u16)0;
                vb[j2][h][tt] = __builtin_bit_cast(__bf16, val);
            }
    }

    // --- S = Q K^T ---
    bf16x8 qf[4], kf[4];
#pragma unroll
    for (int i = 0; i < 4; ++i) {
        int r0 = i * 16 + c; if (r0 > 48) r0 = 48;   // clamp: garbage rows unused
        qf[i] = *(const bf16x8*)(qb + (size_t)r0 * 768 + ko);
        kf[i] = *(const bf16x8*)(qb + (size_t)r0 * 768 + 256 + ko);
    }
    f32x4 s[4][4] = {};
    __builtin_amdgcn_s_setprio(1);
#pragma unroll
    for (int i = 0; i < 4; ++i)
#pragma unroll
        for (int j = 0; j < 4; ++j)
            s[i][j] = __builtin_amdgcn_mfma_f32_16x16x32_bf16(qf[i], kf[j], s[i][j], 0, 0, 0);
    __builtin_amdgcn_s_setprio(0);

    // --- masked softmax in C-layout (row = i*16+g*4+r, col = j*16+c) ---
    const int wh7 = (wi >> 3) * 7, ww7 = (wi & 7) * 7;
    int idj[4]; bool jok[4];
#pragma unroll
    for (int j = 0; j < 4; ++j) {
        int col = j * 16 + c;
        jok[j] = col < LWIN;
        int p = jok[j] ? col : 48;
        idj[j] = region_of(wh7 + p / 7) * 3 + region_of(ww7 + p % 7);
    }
#pragma unroll
    for (int i = 0; i < 4; ++i) {
#pragma unroll
        for (int r = 0; r < 4; ++r) {
            int row = i * 16 + g * 4 + r;
            int p = row < LWIN ? row : 48;
            int idi = region_of(wh7 + p / 7) * 3 + region_of(ww7 + p % 7);
            float mx = -1e30f;
#pragma unroll
            for (int j = 0; j < 4; ++j) {
                float tv = jok[j] ? fmaf(s[i][j][r], 0.17677669529663687f,
                                         (idi == idj[j]) ? 0.f : -100.f)
                                  : -1e30f;
                s[i][j][r] = tv;
                mx = fmaxf(mx, tv);
            }
            for (int o = 8; o; o >>= 1) mx = fmaxf(mx, __shfl_xor(mx, o));
            float ps = 0.f;
#pragma unroll
            for (int j = 0; j < 4; ++j) {
                float e = __expf(s[i][j][r] - mx);
                s[i][j][r] = e; ps += e;
            }
            for (int o = 8; o; o >>= 1) ps += __shfl_xor(ps, o);
            float inv = 1.f / ps;
            if (row < LWIN) {
#pragma unroll
                for (int j = 0; j < 4; ++j)
                    pl[row * 72 + j * 16 + c] = f2bu(s[i][j][r] * inv);
            }
        }
    }
    // per-wave pl: compiler-inserted lgkmcnt orders write->read within the wave

    // --- O = P V (M=64, N=32, K=64) ---
    f32x4 o[4][2] = {};
    __builtin_amdgcn_s_setprio(1);
#pragma unroll
    for (int i = 0; i < 4; ++i) {
        bf16x8 pa0 = *(const bf16x8*)(&pl[(i * 16 + c) * 72 + ko]);
        bf16x8 pa1 = *(const bf16x8*)(&pl[(i * 16 + c) * 72 + ko + 32]);
#pragma unroll
        for (int j2 = 0; j2 < 2; ++j2) {
            o[i][j2] = __builtin_amdgcn_mfma_f32_16x16x32_bf16(pa0, vb[j2][0], o[i][j2], 0, 0, 0);
            o[i][j2] = __builtin_amdgcn_mfma_f32_16x16x32_bf16(pa1, vb[j2][1], o[i][j2], 0, 0, 0);
        }
    }
    __builtin_amdgcn_s_setprio(0);

    __syncthreads();        // all waves done reading their Pl -> U reusable

    // --- phase B: o_t = U[0..16895] (64 x 264), wstage = U+16896 (2 x 8192) ---
    u16* o_t = U;
    u16* wst = U + 16896;
    // issue weight k-chunk 0 stage early (overlaps o_t writes below)
    {
        int cidx = threadIdx.x, n = cidx >> 2, sub = cidx & 3;
        gload_lds16(wpt + (size_t)n * 256 + (sub ^ ((n >> 1) & 3)) * 8, wst + cidx * 8);
        cidx += 512; n = cidx >> 2; sub = cidx & 3;
        gload_lds16(wpt + (size_t)n * 256 + (sub ^ ((n >> 1) & 3)) * 8, wst + cidx * 8);
    }
#pragma unroll
    for (int i = 0; i < 4; ++i)
#pragma unroll
        for (int r = 0; r < 4; ++r) {
            int row = i * 16 + g * 4 + r;
            if (row < LWIN) {
#pragma unroll
                for (int j2 = 0; j2 < 2; ++j2)
                    o_t[row * 264 + head * 32 + j2 * 16 + c] = f2bu(o[i][j2][r]);
            }
        }
    __syncthreads();        // o_t complete (rows >= 49 stale-garbage: discarded)

    // --- proj GEMM: out 64(49)x256, K=256, wave wv owns cols [wv*32, wv*32+32)
    f32x4 acc2[4][2] = {};
    const int kos2 = ((g ^ (lane >> 1)) & 3) * 8;
    int curb = 0;
    for (int it = 0; it < 8; ++it) {
        if (it + 1 < 8) {
            int kc0 = (it + 1) * 32;
            int cidx = threadIdx.x, n = cidx >> 2, sub = cidx & 3;
            gload_lds16(wpt + (size_t)n * 256 + kc0 + (sub ^ ((n >> 1) & 3)) * 8,
                        wst + (curb ^ 1) * 8192 + cidx * 8);
            cidx += 512; n = cidx >> 2; sub = cidx & 3;
            gload_lds16(wpt + (size_t)n * 256 + kc0 + (sub ^ ((n >> 1) & 3)) * 8,
                        wst + (curb ^ 1) * 8192 + cidx * 8);
            asm volatile("s_waitcnt vmcnt(2)" ::: "memory");
        } else {
            asm volatile("s_waitcnt vmcnt(0)" ::: "memory");
        }
        __builtin_amdgcn_s_barrier();
        __builtin_amdgcn_sched_barrier(0);
        bf16x8 af[4], bf2[2];
#pragma unroll
        for (int i = 0; i < 4; ++i)
            af[i] = *(const bf16x8*)(o_t + (i * 16 + c) * 264 + it * 32 + ko);
#pragma unroll
        for (int j2 = 0; j2 < 2; ++j2)
            bf2[j2] = *(const bf16x8*)(wst + curb * 8192 + (wv * 32 + j2 * 16 + c) * 32 + kos2);
        asm volatile("s_waitcnt lgkmcnt(0)" ::: "memory");
        __builtin_amdgcn_sched_barrier(0);
        __builtin_amdgcn_s_barrier();
        __builtin_amdgcn_s_setprio(1);
#pragma unroll
        for (int i = 0; i < 4; ++i)
#pragma unroll
            for (int j2 = 0; j2 < 2; ++j2)
                acc2[i][j2] = __builtin_amdgcn_mfma_f32_16x16x32_bf16(af[i], bf2[j2], acc2[i][j2], 0, 0, 0);
        __builtin_amdgcn_s_setprio(0);
        curb ^= 1;
    }

    // --- epilogue: scatter to x1b (proj_out) via row2tok, + bias ---
#pragma unroll
    for (int j2 = 0; j2 < 2; ++j2) {
        int col = wv * 32 + j2 * 16 + c;
        float bj = pbias[col];
#pragma unroll
        for (int i = 0; i < 4; ++i)
#pragma unroll
            for (int r = 0; r < 4; ++r) {
                int row = i * 16 + g * 4 + r;
                if (row < LWIN) {
                    int tok = row2tok(rowbase + row);
                    x1b[(size_t)tok * 256 + col] = f2bu(acc2[i][j2][r] + bj);
                }
            }
    }
}

extern "C" void kernel_launch(void* const* d_in, const int* in_sizes, int n_in,
                              void* d_out, int out_size, void* d_ws, size_t ws_size,
                              hipStream_t stream) {
    const float* x      = (const float*)d_in[0];
    const float* ln1_g  = (const float*)d_in[1];
    const float* ln1_b  = (const float*)d_in[2];
    const float* ln2_g  = (const float*)d_in[3];
    const float* ln2_b  = (const float*)d_in[4];
    const float* qkv_w  = (const float*)d_in[5];
    const float* qkv_b  = (const float*)d_in[6];
    const float* proj_w = (const float*)d_in[7];
    const float* proj_b = (const float*)d_in[8];
    const float* ffn_w1 = (const float*)d_in[9];
    const float* ffn_b1 = (const float*)d_in[10];
    const float* ffn_w2 = (const float*)d_in[11];
    const float* ffn_b2 = (const float*)d_in[12];
    const float* lscale = (const float*)d_in[13];

    // workspace: total 104,333,312 B (layout unchanged since R6)
    char* wsb = (char*)d_ws;
    u16* wqt  = (u16*)(wsb);
    u16* wpt  = (u16*)(wsb + 393216);
    u16* w1t  = (u16*)(wsb + 524288);
    u16* w2t  = (u16*)(wsb + 1048576);
    u16* P    = (u16*)(wsb + 1572864);
    char* Qb  = wsb + 27262976;
    u16* qkvb = (u16*)Qb;
    u16* x1b  = (u16*)Qb;
    u16* f1c  = (u16*)(Qb + 25690112);

    k_wconv_all<<<768, 256, 0, stream>>>(qkv_w, wqt, proj_w, wpt, ffn_w1, w1t, ffn_w2, w2t);

    k_ln1<<<16 * 98, 256, 0, stream>>>(x, ln1_g, ln1_b, P);
    k_mgemm256<0><<<dim3(196, 6), 512, 0, stream>>>(P, wqt, qkv_b, qkvb, 256, 768);
    // fused attention + proj -> proj_out (x1b, token-scattered bf16)
    k_attnproj<<<1024, 512, 0, stream>>>(qkvb, wpt, proj_b, x1b);
    // x1 = proj_out + transpose(x) (in-place), h2 = LN2(x1) -> P
    k_ln2t<<<16 * 98, 256, 0, stream>>>(x, x1b, ln2_g, ln2_b, P);
    for (int c = 0; c < 2; ++c) {
        k_mgemm256<2><<<dim3(98, 8), 512, 0, stream>>>(P + (size_t)c * FCH * 256, w1t, ffn_b1,
                                                       f1c, 256, 1024);
        k_mgemm128<3><<<dim3(196, 2), 256, 0, stream>>>(f1c, w2t, ffn_b2, d_out, 1024, 256,
                                                        x1b, lscale, c * FCH);
    }
}

// Round 17
// 241.399 us; speedup vs baseline: 1.2775x; 1.1172x over previous
//
#include <hip/hip_runtime.h>
#include <hip/hip_bf16.h>
#include <math.h>

typedef unsigned short u16;
typedef __bf16 bf16x8 __attribute__((ext_vector_type(8)));
typedef float  f32x4  __attribute__((ext_vector_type(4)));

#define DIMC 256
#define QSZ  56
#define WSZ  7
#define SSZ  3
#define LWIN 49
#define NWIN 64
#define HW   3136          // 56*56
#define NTOK 50176         // 16*3136
#define FFWD 1024
#define FCH  25088         // NTOK/2 ffn chunk rows

__device__ __forceinline__ u16 f2bu(float f) {
    __hip_bfloat16 h = __float2bfloat16(f);
    return __builtin_bit_cast(u16, h);
}
__device__ __forceinline__ float bu2f(u16 u) {
    unsigned v = (unsigned)u << 16;
    return __builtin_bit_cast(float, v);
}
__device__ __forceinline__ void gload_lds16(const void* g, void* l) {
    __builtin_amdgcn_global_load_lds((const __attribute__((address_space(1))) void*)g,
                                     (__attribute__((address_space(3))) void*)l, 16, 0, 0);
}

// XCD-bijective swizzle (m204): nwg % 8 == 0 required. Consecutive swz ids
// share an A-panel; each XCD owns a contiguous chunk of panels.
__device__ __forceinline__ int xcd_swz(int flat, int nwg) {
    int q = nwg >> 3;
    return (flat & 7) * q + (flat >> 3);
}

__device__ __forceinline__ int region_of(int h) {
    return (h < 49) ? 0 : ((h < 53) ? 1 : 2);
}

// partitioned row m = ((b*64 + wi)*49 + p) -> flat token index (with roll by -3)
__device__ __forceinline__ int row2tok(int m) {
    int b  = m / (NWIN * LWIN);
    int r  = m - b * (NWIN * LWIN);
    int wi = r / LWIN;
    int p  = r - wi * LWIN;
    int wh = wi >> 3, ww = wi & 7;
    int ph = p / 7,   pw = p - ph * 7;
    int hr = wh * 7 + ph, wr = ww * 7 + pw;
    int hs = hr + SSZ; if (hs >= QSZ) hs -= QSZ;
    int ws2 = wr + SSZ; if (ws2 >= QSZ) ws2 -= QSZ;
    return b * HW + hs * QSZ + ws2;
}

// ---------------- merged weight transpose + bf16 convert (4 weights) ----------
__device__ __forceinline__ void wconv_body(const float* __restrict__ W,
        u16* __restrict__ Wt, int K, int N, int bx, int by, int t) {
    __shared__ float tile[32][33];
    int k0 = bx * 32, n0 = by * 32;
    int tx = t & 31, ty = t >> 5;
    for (int kk = ty; kk < 32; kk += 8)
        tile[kk][tx] = W[(size_t)(k0 + kk) * N + n0 + tx];
    __syncthreads();
    for (int nn = ty; nn < 32; nn += 8)
        Wt[(size_t)(n0 + nn) * K + k0 + tx] = f2bu(tile[tx][nn]);
}

__global__ __launch_bounds__(256) void k_wconv_all(
        const float* __restrict__ qkv_w, u16* __restrict__ wqt,
        const float* __restrict__ proj_w, u16* __restrict__ wpt,
        const float* __restrict__ ffn_w1, u16* __restrict__ w1t,
        const float* __restrict__ ffn_w2, u16* __restrict__ w2t) {
    int b = blockIdx.x, t = threadIdx.x;
    if (b < 192)        wconv_body(qkv_w, wqt, 256, 768, b & 7, b >> 3, t);
    else if (b < 256) { b -= 192; wconv_body(proj_w, wpt, 256, 256,  b & 7, b >> 3, t); }
    else if (b < 512) { b -= 256; wconv_body(ffn_w1, w1t, 256, 1024, b & 7, b >> 3, t); }
    else              { b -= 512; wconv_body(ffn_w2, w2t, 1024, 256, b & 31, b >> 5, t); }
}

// ---------------- K1: BCHW -> token-major transpose + LN1 -> bf16 -------------
__global__ __launch_bounds__(256) void k_ln1(const float* __restrict__ x,
        const float* __restrict__ g, const float* __restrict__ be,
        u16* __restrict__ hln) {
    __shared__ float tile[32][257];
    __shared__ float msh[32], rsh[32];
    int blk = blockIdx.x;            // 16 * 98
    int b   = blk / 98;
    int hw0 = (blk - b * 98) * 32;
    int t   = threadIdx.x;
    int tx  = t & 31, ty = t >> 5;
    for (int c = ty; c < 256; c += 8)
        tile[tx][c] = x[(size_t)(b * 256 + c) * HW + hw0 + tx];
    __syncthreads();
    int row = t >> 3, sub = t & 7;
    float s = 0.f, sq = 0.f;
    for (int c = sub * 32; c < sub * 32 + 32; ++c) {
        float v = tile[row][c]; s += v; sq += v * v;
    }
    for (int o = 4; o; o >>= 1) { s += __shfl_down(s, o, 8); sq += __shfl_down(sq, o, 8); }
    if (sub == 0) {
        float m   = s * (1.f / 256.f);
        float var = sq * (1.f / 256.f) - m * m;
        msh[row] = m; rsh[row] = rsqrtf(var + 1e-5f);
    }
    __syncthreads();
    float gg = g[t], bb = be[t];
    for (int r2 = 0; r2 < 32; ++r2) {
        float v = tile[r2][t];
        hln[(size_t)(b * HW + hw0 + r2) * 256 + t] = f2bu((v - msh[r2]) * rsh[r2] * gg + bb);
    }
}

// ---------------- LN2 + residual: x1 = proj_out + transpose(x); h2 = LN(x1) ---
__global__ __launch_bounds__(256) void k_ln2t(const float* __restrict__ x,
        u16* __restrict__ x1b, const float* __restrict__ g,
        const float* __restrict__ be, u16* __restrict__ h2) {
    __shared__ float tile[32][257];
    __shared__ float msh[32], rsh[32];
    int blk = blockIdx.x;            // 16 * 98
    int b   = blk / 98;
    int hw0 = (blk - b * 98) * 32;
    int t   = threadIdx.x;
    int tx  = t & 31, ty = t >> 5;
    for (int c = ty; c < 256; c += 8)
        tile[tx][c] = x[(size_t)(b * 256 + c) * HW + hw0 + tx];
    __syncthreads();
    size_t base = (size_t)b * HW + hw0;
    for (int r2 = 0; r2 < 32; ++r2) {
        float v = tile[r2][t] + bu2f(x1b[(base + r2) * 256 + t]);
        tile[r2][t] = v;
        x1b[(base + r2) * 256 + t] = f2bu(v);
    }
    __syncthreads();
    int row = t >> 3, sub = t & 7;
    float s = 0.f, sq = 0.f;
    for (int c = sub * 32; c < sub * 32 + 32; ++c) {
        float v = tile[row][c]; s += v; sq += v * v;
    }
    for (int o = 4; o; o >>= 1) { s += __shfl_down(s, o, 8); sq += __shfl_down(sq, o, 8); }
    if (sub == 0) {
        float m   = s * (1.f / 256.f);
        float var = sq * (1.f / 256.f) - m * m;
        msh[row] = m; rsh[row] = rsqrtf(var + 1e-5f);
    }
    __syncthreads();
    float gg = g[t], bb = be[t];
    for (int r2 = 0; r2 < 32; ++r2) {
        float v = tile[r2][t];
        h2[(base + r2) * 256 + t] = f2bu((v - msh[r2]) * rsh[r2] * gg + bb);
    }
}

// ---------------- MFMA GEMM, 256x128 tile, 512 thr (qkv / ffn1) ---------------
// R13-verified loop (2-buffer depth-1, barriers A+B, vmcnt(3), T2 swizzle,
// conflicts = 0) + T1 XCD-bijective 1-D grid: consecutive swz share the
// A-panel so it is fetched once per XCD L2 instead of GY times from HBM.
// MODE 0: qkv -> bf16 +bias (N=768, A gathered); MODE 2: ffn1 -> bf16 relu.
template<int MODE>
__global__ __launch_bounds__(512) void k_mgemm256(
        const u16* __restrict__ A, const u16* __restrict__ Bt,
        const float* __restrict__ bias, void* __restrict__ Cv, int K, int N,
        int gy) {
    __shared__ __align__(16) u16 As[2][256 * 32];
    __shared__ __align__(16) u16 Bs[2][128 * 32];
    const int swz = xcd_swz(blockIdx.x, gridDim.x);
    const int mb = swz / gy, nb = swz - mb * gy;
    const int m0 = mb * 256, n0 = nb * 128;
    const int t = threadIdx.x, lane = t & 63;
    const int wv = t >> 6, wr = wv >> 1, wc = wv & 1;

    const int kc = (t & 3) ^ ((t >> 3) & 3);
    int ar0 = m0 + (t >> 2), ar1 = m0 + 128 + (t >> 2);
    if (MODE == 0) { ar0 = row2tok(ar0); ar1 = row2tok(ar1); }
    const u16* gA0 = A  + (size_t)ar0 * K + kc * 8;
    const u16* gA1 = A  + (size_t)ar1 * K + kc * 8;
    const u16* gB0 = Bt + (size_t)(n0 + (t >> 2)) * K + kc * 8;

    f32x4 acc[4][4] = {};
    const int ra = wr * 64 + (lane & 15);
    const int rb = wc * 64 + (lane & 15);
    const int kos = (((lane >> 4) ^ (lane >> 1)) & 3) * 8;
    const int nIter = K >> 5;

    gload_lds16(gA0, As[0] + t * 8);
    gload_lds16(gA1, As[0] + 4096 + t * 8);
    gload_lds16(gB0, Bs[0] + t * 8);

    int cur = 0;
    for (int it = 0; it < nIter; ++it) {
        if (it + 1 < nIter) {
            const int k1 = (it + 1) << 5;
            gload_lds16(gA0 + k1, As[cur ^ 1] + t * 8);
            gload_lds16(gA1 + k1, As[cur ^ 1] + 4096 + t * 8);
            gload_lds16(gB0 + k1, Bs[cur ^ 1] + t * 8);
            asm volatile("s_waitcnt vmcnt(3)" ::: "memory");
        } else {
            asm volatile("s_waitcnt vmcnt(0)" ::: "memory");
        }
        __builtin_amdgcn_s_barrier();
        __builtin_amdgcn_sched_barrier(0);
        bf16x8 af[4], bfr[4];
#pragma unroll
        for (int i = 0; i < 4; ++i)
            af[i] = *(const bf16x8*)(As[cur] + (ra + i * 16) * 32 + kos);
#pragma unroll
        for (int j = 0; j < 4; ++j)
            bfr[j] = *(const bf16x8*)(Bs[cur] + (rb + ((j & 1) * 16 + (j >> 1) * 32)) * 32 + kos);
        asm volatile("s_waitcnt lgkmcnt(0)" ::: "memory");
        __builtin_amdgcn_sched_barrier(0);
        __builtin_amdgcn_s_barrier();
#pragma unroll
        for (int i = 0; i < 4; ++i)
#pragma unroll
            for (int j = 0; j < 4; ++j)
                acc[i][j] = __builtin_amdgcn_mfma_f32_16x16x32_bf16(af[i], bfr[j], acc[i][j], 0, 0, 0);
        cur ^= 1;
    }

    const int rowb = m0 + wr * 64 + ((lane >> 4) * 4);
    u16* Cb = (u16*)Cv;
#pragma unroll
    for (int j = 0; j < 4; ++j) {
        int col = n0 + wc * 64 + ((j & 1) * 16 + (j >> 1) * 32) + (lane & 15);
        float bj = bias[col];
#pragma unroll
        for (int i = 0; i < 4; ++i) {
            int rw = rowb + i * 16;
#pragma unroll
            for (int r = 0; r < 4; ++r) {
                float v = acc[i][j][r] + bj;
                if (MODE == 2) v = fmaxf(v, 0.f);
                Cb[(size_t)(rw + r) * N + col] = f2bu(v);
            }
        }
    }
}

// ---------------- MFMA GEMM, 128x128 tile, 256 thr (ffn2) ---------------------
// R10-verified loop + T2 swizzle + T1 XCD-bijective 1-D grid.
// MODE 3: ffn2 -> fp32 BCHW d_out = x1(bf16) + ls*(acc+bias)   (N=256)
template<int MODE>
__global__ __launch_bounds__(256) void k_mgemm128(
        const u16* __restrict__ A, const u16* __restrict__ Bt,
        const float* __restrict__ bias, void* __restrict__ Cv,
        int K, int N, const void* __restrict__ extra,
        const float* __restrict__ extra2, int grow0, int gy) {
    __shared__ __align__(16) u16 As[2][128 * 32];
    __shared__ __align__(16) u16 Bs[2][128 * 32];
    const int swz = xcd_swz(blockIdx.x, gridDim.x);
    const int mb = swz / gy, nb = swz - mb * gy;
    const int m0 = mb * 128, n0 = nb * 128;
    const int t = threadIdx.x, lane = t & 63;
    const int wv = t >> 6, wr = wv >> 1, wc = wv & 1;

    const int kc = (t & 3) ^ ((t >> 3) & 3);
    const u16* gA0 = A  + (size_t)(m0 + (t >> 2)) * K + kc * 8;
    const u16* gA1 = A  + (size_t)(m0 + 64 + (t >> 2)) * K + kc * 8;
    const u16* gB0 = Bt + (size_t)(n0 + (t >> 2)) * K + kc * 8;
    const u16* gB1 = Bt + (size_t)(n0 + 64 + (t >> 2)) * K + kc * 8;

    f32x4 acc[4][4] = {};
    const int ra = wr * 64 + (lane & 15);
    const int rb = wc * 64 + (lane & 15);
    const int kos = (((lane >> 4) ^ (lane >> 1)) & 3) * 8;
    const int nIter = K >> 5;

    gload_lds16(gA0, As[0] + t * 8);
    gload_lds16(gA1, As[0] + 2048 + t * 8);
    gload_lds16(gB0, Bs[0] + t * 8);
    gload_lds16(gB1, Bs[0] + 2048 + t * 8);

    int cur = 0;
    for (int it = 0; it < nIter; ++it) {
        if (it + 1 < nIter) {
            const int k1 = (it + 1) << 5;
            gload_lds16(gA0 + k1, As[cur ^ 1] + t * 8);
            gload_lds16(gA1 + k1, As[cur ^ 1] + 2048 + t * 8);
            gload_lds16(gB0 + k1, Bs[cur ^ 1] + t * 8);
            gload_lds16(gB1 + k1, Bs[cur ^ 1] + 2048 + t * 8);
            asm volatile("s_waitcnt vmcnt(4)" ::: "memory");
        } else {
            asm volatile("s_waitcnt vmcnt(0)" ::: "memory");
        }
        __builtin_amdgcn_s_barrier();
        __builtin_amdgcn_sched_barrier(0);
        bf16x8 af[4], bfr[4];
#pragma unroll
        for (int i = 0; i < 4; ++i)
            af[i] = *(const bf16x8*)(As[cur] + (ra + i * 16) * 32 + kos);
#pragma unroll
        for (int j = 0; j < 4; ++j)
            bfr[j] = *(const bf16x8*)(Bs[cur] + (rb + j * 16) * 32 + kos);
        asm volatile("s_waitcnt lgkmcnt(0)" ::: "memory");
        __builtin_amdgcn_sched_barrier(0);
        __builtin_amdgcn_s_barrier();
#pragma unroll
        for (int i = 0; i < 4; ++i)
#pragma unroll
            for (int j = 0; j < 4; ++j)
                acc[i][j] = __builtin_amdgcn_mfma_f32_16x16x32_bf16(af[i], bfr[j], acc[i][j], 0, 0, 0);
        cur ^= 1;
    }

    const int colb = n0 + wc * 64 + (lane & 15);
    const int rowb = m0 + wr * 64 + ((lane >> 4) * 4);

    float* C = (float*)Cv;
    const u16* xr = (const u16*)extra;       // x1 bf16
#pragma unroll
    for (int j = 0; j < 4; ++j) {
        int col = colb + j * 16;
        float bj = bias[col], lj = extra2[col];
#pragma unroll
        for (int i = 0; i < 4; ++i) {
            int g  = grow0 + rowb + i * 16;   // 4-row pack never crosses batch
            int b  = g / HW, hw = g - b * HW;
            f32x4 o;
#pragma unroll
            for (int r = 0; r < 4; ++r)
                o[r] = bu2f(xr[(size_t)(g + r) * 256 + col]) + lj * (acc[i][j][r] + bj);
            *(f32x4*)(C + ((size_t)(b * 256 + col)) * HW + hw) = o;
        }
    }
}

// ---------------- fused attention + proj: one BLOCK per window ----------------
// (unchanged from R16-verified kernel)
__global__ __launch_bounds__(512) void k_attnproj(const u16* __restrict__ qkv,
        const u16* __restrict__ wpt, const float* __restrict__ pbias,
        u16* __restrict__ x1b) {
    __shared__ __align__(16) u16 U[33280];
    const int wv = threadIdx.x >> 6, lane = threadIdx.x & 63;
    const int win = blockIdx.x, head = wv, wi = win & 63;
    const int rowbase = win * LWIN;
    const int g = lane >> 4, c = lane & 15, ko = g * 8;
    const u16* qb = qkv + (size_t)rowbase * 768 + head * 32;
    u16* pl = U + wv * (LWIN * 72);

    bf16x8 vb[2][2];
#pragma unroll
    for (int j2 = 0; j2 < 2; ++j2) {
        int d = j2 * 16 + c;
#pragma unroll
        for (int h = 0; h < 2; ++h)
#pragma unroll
            for (int tt = 0; tt < 8; ++tt) {
                int k = h * 32 + ko + tt;
                u16 val = (k < LWIN) ? qb[(size_t)k * 768 + 512 + d] : (u16)0;
                vb[j2][h][tt] = __builtin_bit_cast(__bf16, val);
            }
    }

    bf16x8 qf[4], kf[4];
#pragma unroll
    for (int i = 0; i < 4; ++i) {
        int r0 = i * 16 + c; if (r0 > 48) r0 = 48;
        qf[i] = *(const bf16x8*)(qb + (size_t)r0 * 768 + ko);
        kf[i] = *(const bf16x8*)(qb + (size_t)r0 * 768 + 256 + ko);
    }
    f32x4 s[4][4] = {};
    __builtin_amdgcn_s_setprio(1);
#pragma unroll
    for (int i = 0; i < 4; ++i)
#pragma unroll
        for (int j = 0; j < 4; ++j)
            s[i][j] = __builtin_amdgcn_mfma_f32_16x16x32_bf16(qf[i], kf[j], s[i][j], 0, 0, 0);
    __builtin_amdgcn_s_setprio(0);

    const int wh7 = (wi >> 3) * 7, ww7 = (wi & 7) * 7;
    int idj[4]; bool jok[4];
#pragma unroll
    for (int j = 0; j < 4; ++j) {
        int col = j * 16 + c;
        jok[j] = col < LWIN;
        int p = jok[j] ? col : 48;
        idj[j] = region_of(wh7 + p / 7) * 3 + region_of(ww7 + p % 7);
    }
#pragma unroll
    for (int i = 0; i < 4; ++i) {
#pragma unroll
        for (int r = 0; r < 4; ++r) {
            int row = i * 16 + g * 4 + r;
            int p = row < LWIN ? row : 48;
            int idi = region_of(wh7 + p / 7) * 3 + region_of(ww7 + p % 7);
            float mx = -1e30f;
#pragma unroll
            for (int j = 0; j < 4; ++j) {
                float tv = jok[j] ? fmaf(s[i][j][r], 0.17677669529663687f,
                                         (idi == idj[j]) ? 0.f : -100.f)
                                  : -1e30f;
                s[i][j][r] = tv;
                mx = fmaxf(mx, tv);
            }
            for (int o = 8; o; o >>= 1) mx = fmaxf(mx, __shfl_xor(mx, o));
            float ps = 0.f;
#pragma unroll
            for (int j = 0; j < 4; ++j) {
                float e = __expf(s[i][j][r] - mx);
                s[i][j][r] = e; ps += e;
            }
            for (int o = 8; o; o >>= 1) ps += __shfl_xor(ps, o);
            float inv = 1.f / ps;
            if (row < LWIN) {
#pragma unroll
                for (int j = 0; j < 4; ++j)
                    pl[row * 72 + j * 16 + c] = f2bu(s[i][j][r] * inv);
            }
        }
    }

    f32x4 o[4][2] = {};
    __builtin_amdgcn_s_setprio(1);
#pragma unroll
    for (int i = 0; i < 4; ++i) {
        bf16x8 pa0 = *(const bf16x8*)(&pl[(i * 16 + c) * 72 + ko]);
        bf16x8 pa1 = *(const bf16x8*)(&pl[(i * 16 + c) * 72 + ko + 32]);
#pragma unroll
        for (int j2 = 0; j2 < 2; ++j2) {
            o[i][j2] = __builtin_amdgcn_mfma_f32_16x16x32_bf16(pa0, vb[j2][0], o[i][j2], 0, 0, 0);
            o[i][j2] = __builtin_amdgcn_mfma_f32_16x16x32_bf16(pa1, vb[j2][1], o[i][j2], 0, 0, 0);
        }
    }
    __builtin_amdgcn_s_setprio(0);

    __syncthreads();

    u16* o_t = U;
    u16* wst = U + 16896;
    {
        int cidx = threadIdx.x, n = cidx >> 2, sub = cidx & 3;
        gload_lds16(wpt + (size_t)n * 256 + (sub ^ ((n >> 1) & 3)) * 8, wst + cidx * 8);
        cidx += 512; n = cidx >> 2; sub = cidx & 3;
        gload_lds16(wpt + (size_t)n * 256 + (sub ^ ((n >> 1) & 3)) * 8, wst + cidx * 8);
    }
#pragma unroll
    for (int i = 0; i < 4; ++i)
#pragma unroll
        for (int r = 0; r < 4; ++r) {
            int row = i * 16 + g * 4 + r;
            if (row < LWIN) {
#pragma unroll
                for (int j2 = 0; j2 < 2; ++j2)
                    o_t[row * 264 + head * 32 + j2 * 16 + c] = f2bu(o[i][j2][r]);
            }
        }
    __syncthreads();

    f32x4 acc2[4][2] = {};
    const int kos2 = ((g ^ (lane >> 1)) & 3) * 8;
    int curb = 0;
    for (int it = 0; it < 8; ++it) {
        if (it + 1 < 8) {
            int kc0 = (it + 1) * 32;
            int cidx = threadIdx.x, n = cidx >> 2, sub = cidx & 3;
            gload_lds16(wpt + (size_t)n * 256 + kc0 + (sub ^ ((n >> 1) & 3)) * 8,
                        wst + (curb ^ 1) * 8192 + cidx * 8);
            cidx += 512; n = cidx >> 2; sub = cidx & 3;
            gload_lds16(wpt + (size_t)n * 256 + kc0 + (sub ^ ((n >> 1) & 3)) * 8,
                        wst + (curb ^ 1) * 8192 + cidx * 8);
            asm volatile("s_waitcnt vmcnt(2)" ::: "memory");
        } else {
            asm volatile("s_waitcnt vmcnt(0)" ::: "memory");
        }
        __builtin_amdgcn_s_barrier();
        __builtin_amdgcn_sched_barrier(0);
        bf16x8 af[4], bf2[2];
#pragma unroll
        for (int i = 0; i < 4; ++i)
            af[i] = *(const bf16x8*)(o_t + (i * 16 + c) * 264 + it * 32 + ko);
#pragma unroll
        for (int j2 = 0; j2 < 2; ++j2)
            bf2[j2] = *(const bf16x8*)(wst + curb * 8192 + (wv * 32 + j2 * 16 + c) * 32 + kos2);
        asm volatile("s_waitcnt lgkmcnt(0)" ::: "memory");
        __builtin_amdgcn_sched_barrier(0);
        __builtin_amdgcn_s_barrier();
        __builtin_amdgcn_s_setprio(1);
#pragma unroll
        for (int i = 0; i < 4; ++i)
#pragma unroll
            for (int j2 = 0; j2 < 2; ++j2)
                acc2[i][j2] = __builtin_amdgcn_mfma_f32_16x16x32_bf16(af[i], bf2[j2], acc2[i][j2], 0, 0, 0);
        __builtin_amdgcn_s_setprio(0);
        curb ^= 1;
    }

#pragma unroll
    for (int j2 = 0; j2 < 2; ++j2) {
        int col = wv * 32 + j2 * 16 + c;
        float bj = pbias[col];
#pragma unroll
        for (int i = 0; i < 4; ++i)
#pragma unroll
            for (int r = 0; r < 4; ++r) {
                int row = i * 16 + g * 4 + r;
                if (row < LWIN) {
                    int tok = row2tok(rowbase + row);
                    x1b[(size_t)tok * 256 + col] = f2bu(acc2[i][j2][r] + bj);
                }
            }
    }
}

extern "C" void kernel_launch(void* const* d_in, const int* in_sizes, int n_in,
                              void* d_out, int out_size, void* d_ws, size_t ws_size,
                              hipStream_t stream) {
    const float* x      = (const float*)d_in[0];
    const float* ln1_g  = (const float*)d_in[1];
    const float* ln1_b  = (const float*)d_in[2];
    const float* ln2_g  = (const float*)d_in[3];
    const float* ln2_b  = (const float*)d_in[4];
    const float* qkv_w  = (const float*)d_in[5];
    const float* qkv_b  = (const float*)d_in[6];
    const float* proj_w = (const float*)d_in[7];
    const float* proj_b = (const float*)d_in[8];
    const float* ffn_w1 = (const float*)d_in[9];
    const float* ffn_b1 = (const float*)d_in[10];
    const float* ffn_w2 = (const float*)d_in[11];
    const float* ffn_b2 = (const float*)d_in[12];
    const float* lscale = (const float*)d_in[13];

    // workspace: total 104,333,312 B (layout unchanged since R6)
    char* wsb = (char*)d_ws;
    u16* wqt  = (u16*)(wsb);
    u16* wpt  = (u16*)(wsb + 393216);
    u16* w1t  = (u16*)(wsb + 524288);
    u16* w2t  = (u16*)(wsb + 1048576);
    u16* P    = (u16*)(wsb + 1572864);
    char* Qb  = wsb + 27262976;
    u16* qkvb = (u16*)Qb;
    u16* x1b  = (u16*)Qb;
    u16* f1c  = (u16*)(Qb + 25690112);

    k_wconv_all<<<768, 256, 0, stream>>>(qkv_w, wqt, proj_w, wpt, ffn_w1, w1t, ffn_w2, w2t);

    k_ln1<<<16 * 98, 256, 0, stream>>>(x, ln1_g, ln1_b, P);
    // qkv: 196 m-blocks x 6 n-blocks, XCD-swizzled 1-D grid (1176 % 8 == 0)
    k_mgemm256<0><<<1176, 512, 0, stream>>>(P, wqt, qkv_b, qkvb, 256, 768, 6);
    // fused attention + proj -> proj_out (x1b, token-scattered bf16)
    k_attnproj<<<1024, 512, 0, stream>>>(qkvb, wpt, proj_b, x1b);
    // x1 = proj_out + transpose(x) (in-place), h2 = LN2(x1) -> P
    k_ln2t<<<16 * 98, 256, 0, stream>>>(x, x1b, ln2_g, ln2_b, P);
    for (int c = 0; c < 2; ++c) {
        // ffn1: 98 x 8 = 784 (784 % 8 == 0)
        k_mgemm256<2><<<784, 512, 0, stream>>>(P + (size_t)c * FCH * 256, w1t, ffn_b1,
                                               f1c, 256, 1024, 8);
        // ffn2: 196 x 2 = 392 (392 % 8 == 0)
        k_mgemm128<3><<<392, 256, 0, stream>>>(f1c, w2t, ffn_b2, d_out, 1024, 256,
                                               x1b, lscale, c * FCH, 2);
    }
}

// Round 18
// 241.304 us; speedup vs baseline: 1.2780x; 1.0004x over previous
//
#include <hip/hip_runtime.h>
#include <hip/hip_bf16.h>
#include <math.h>

typedef unsigned short u16;
typedef __bf16 bf16x8 __attribute__((ext_vector_type(8)));
typedef float  f32x4  __attribute__((ext_vector_type(4)));

#define DIMC 256
#define QSZ  56
#define WSZ  7
#define SSZ  3
#define LWIN 49
#define NWIN 64
#define HW   3136          // 56*56
#define NTOK 50176         // 16*3136
#define FFWD 1024
#define FCH  25088         // NTOK/2 ffn chunk rows

__device__ __forceinline__ u16 f2bu(float f) {
    __hip_bfloat16 h = __float2bfloat16(f);
    return __builtin_bit_cast(u16, h);
}
__device__ __forceinline__ float bu2f(u16 u) {
    unsigned v = (unsigned)u << 16;
    return __builtin_bit_cast(float, v);
}
__device__ __forceinline__ void gload_lds16(const void* g, void* l) {
    __builtin_amdgcn_global_load_lds((const __attribute__((address_space(1))) void*)g,
                                     (__attribute__((address_space(3))) void*)l, 16, 0, 0);
}

// XCD-bijective swizzle (m204): nwg % 8 == 0 required. Consecutive swz ids
// share an A-panel; each XCD owns a contiguous chunk of panels.
__device__ __forceinline__ int xcd_swz(int flat, int nwg) {
    int q = nwg >> 3;
    return (flat & 7) * q + (flat >> 3);
}

__device__ __forceinline__ int region_of(int h) {
    return (h < 49) ? 0 : ((h < 53) ? 1 : 2);
}

// partitioned row m = ((b*64 + wi)*49 + p) -> flat token index (with roll by -3)
__device__ __forceinline__ int row2tok(int m) {
    int b  = m / (NWIN * LWIN);
    int r  = m - b * (NWIN * LWIN);
    int wi = r / LWIN;
    int p  = r - wi * LWIN;
    int wh = wi >> 3, ww = wi & 7;
    int ph = p / 7,   pw = p - ph * 7;
    int hr = wh * 7 + ph, wr = ww * 7 + pw;
    int hs = hr + SSZ; if (hs >= QSZ) hs -= QSZ;
    int ws2 = wr + SSZ; if (ws2 >= QSZ) ws2 -= QSZ;
    return b * HW + hs * QSZ + ws2;
}

// ---------------- merged weight transpose + bf16 convert (4 weights) ----------
__device__ __forceinline__ void wconv_body(const float* __restrict__ W,
        u16* __restrict__ Wt, int K, int N, int bx, int by, int t) {
    __shared__ float tile[32][33];
    int k0 = bx * 32, n0 = by * 32;
    int tx = t & 31, ty = t >> 5;
    for (int kk = ty; kk < 32; kk += 8)
        tile[kk][tx] = W[(size_t)(k0 + kk) * N + n0 + tx];
    __syncthreads();
    for (int nn = ty; nn < 32; nn += 8)
        Wt[(size_t)(n0 + nn) * K + k0 + tx] = f2bu(tile[tx][nn]);
}

__global__ __launch_bounds__(256) void k_wconv_all(
        const float* __restrict__ qkv_w, u16* __restrict__ wqt,
        const float* __restrict__ proj_w, u16* __restrict__ wpt,
        const float* __restrict__ ffn_w1, u16* __restrict__ w1t,
        const float* __restrict__ ffn_w2, u16* __restrict__ w2t) {
    int b = blockIdx.x, t = threadIdx.x;
    if (b < 192)        wconv_body(qkv_w, wqt, 256, 768, b & 7, b >> 3, t);
    else if (b < 256) { b -= 192; wconv_body(proj_w, wpt, 256, 256,  b & 7, b >> 3, t); }
    else if (b < 512) { b -= 256; wconv_body(ffn_w1, w1t, 256, 1024, b & 7, b >> 3, t); }
    else              { b -= 512; wconv_body(ffn_w2, w2t, 1024, 256, b & 31, b >> 5, t); }
}

// ---------------- K1: BCHW -> token-major transpose + LN1 -> bf16 -------------
__global__ __launch_bounds__(256) void k_ln1(const float* __restrict__ x,
        const float* __restrict__ g, const float* __restrict__ be,
        u16* __restrict__ hln) {
    __shared__ float tile[32][257];
    __shared__ float msh[32], rsh[32];
    int blk = blockIdx.x;            // 16 * 98
    int b   = blk / 98;
    int hw0 = (blk - b * 98) * 32;
    int t   = threadIdx.x;
    int tx  = t & 31, ty = t >> 5;
    for (int c = ty; c < 256; c += 8)
        tile[tx][c] = x[(size_t)(b * 256 + c) * HW + hw0 + tx];
    __syncthreads();
    int row = t >> 3, sub = t & 7;
    float s = 0.f, sq = 0.f;
    for (int c = sub * 32; c < sub * 32 + 32; ++c) {
        float v = tile[row][c]; s += v; sq += v * v;
    }
    for (int o = 4; o; o >>= 1) { s += __shfl_down(s, o, 8); sq += __shfl_down(sq, o, 8); }
    if (sub == 0) {
        float m   = s * (1.f / 256.f);
        float var = sq * (1.f / 256.f) - m * m;
        msh[row] = m; rsh[row] = rsqrtf(var + 1e-5f);
    }
    __syncthreads();
    float gg = g[t], bb = be[t];
    for (int r2 = 0; r2 < 32; ++r2) {
        float v = tile[r2][t];
        hln[(size_t)(b * HW + hw0 + r2) * 256 + t] = f2bu((v - msh[r2]) * rsh[r2] * gg + bb);
    }
}

// ---------------- LN2 + residual: x1 = proj_out + transpose(x); h2 = LN(x1) ---
__global__ __launch_bounds__(256) void k_ln2t(const float* __restrict__ x,
        u16* __restrict__ x1b, const float* __restrict__ g,
        const float* __restrict__ be, u16* __restrict__ h2) {
    __shared__ float tile[32][257];
    __shared__ float msh[32], rsh[32];
    int blk = blockIdx.x;            // 16 * 98
    int b   = blk / 98;
    int hw0 = (blk - b * 98) * 32;
    int t   = threadIdx.x;
    int tx  = t & 31, ty = t >> 5;
    for (int c = ty; c < 256; c += 8)
        tile[tx][c] = x[(size_t)(b * 256 + c) * HW + hw0 + tx];
    __syncthreads();
    size_t base = (size_t)b * HW + hw0;
    for (int r2 = 0; r2 < 32; ++r2) {
        float v = tile[r2][t] + bu2f(x1b[(base + r2) * 256 + t]);
        tile[r2][t] = v;
        x1b[(base + r2) * 256 + t] = f2bu(v);
    }
    __syncthreads();
    int row = t >> 3, sub = t & 7;
    float s = 0.f, sq = 0.f;
    for (int c = sub * 32; c < sub * 32 + 32; ++c) {
        float v = tile[row][c]; s += v; sq += v * v;
    }
    for (int o = 4; o; o >>= 1) { s += __shfl_down(s, o, 8); sq += __shfl_down(sq, o, 8); }
    if (sub == 0) {
        float m   = s * (1.f / 256.f);
        float var = sq * (1.f / 256.f) - m * m;
        msh[row] = m; rsh[row] = rsqrtf(var + 1e-5f);
    }
    __syncthreads();
    float gg = g[t], bb = be[t];
    for (int r2 = 0; r2 < 32; ++r2) {
        float v = tile[r2][t];
        h2[(base + r2) * 256 + t] = f2bu((v - msh[r2]) * rsh[r2] * gg + bb);
    }
}

// ---------------- MFMA GEMM, 256x128 tile, 512 thr (qkv / ffn1) ---------------
// R13-verified loop (2-buffer depth-1, barriers A+B, vmcnt(3), T2 swizzle,
// conflicts = 0) + T1 XCD-bijective 1-D grid (verified R17: -28 us).
// MODE 0: qkv -> bf16 +bias (N=768, A gathered); MODE 2: ffn1 -> bf16 relu.
template<int MODE>
__global__ __launch_bounds__(512) void k_mgemm256(
        const u16* __restrict__ A, const u16* __restrict__ Bt,
        const float* __restrict__ bias, void* __restrict__ Cv, int K, int N,
        int gy) {
    __shared__ __align__(16) u16 As[2][256 * 32];
    __shared__ __align__(16) u16 Bs[2][128 * 32];
    const int swz = xcd_swz(blockIdx.x, gridDim.x);
    const int mb = swz / gy, nb = swz - mb * gy;
    const int m0 = mb * 256, n0 = nb * 128;
    const int t = threadIdx.x, lane = t & 63;
    const int wv = t >> 6, wr = wv >> 1, wc = wv & 1;

    const int kc = (t & 3) ^ ((t >> 3) & 3);
    int ar0 = m0 + (t >> 2), ar1 = m0 + 128 + (t >> 2);
    if (MODE == 0) { ar0 = row2tok(ar0); ar1 = row2tok(ar1); }
    const u16* gA0 = A  + (size_t)ar0 * K + kc * 8;
    const u16* gA1 = A  + (size_t)ar1 * K + kc * 8;
    const u16* gB0 = Bt + (size_t)(n0 + (t >> 2)) * K + kc * 8;

    f32x4 acc[4][4] = {};
    const int ra = wr * 64 + (lane & 15);
    const int rb = wc * 64 + (lane & 15);
    const int kos = (((lane >> 4) ^ (lane >> 1)) & 3) * 8;
    const int nIter = K >> 5;

    gload_lds16(gA0, As[0] + t * 8);
    gload_lds16(gA1, As[0] + 4096 + t * 8);
    gload_lds16(gB0, Bs[0] + t * 8);

    int cur = 0;
    for (int it = 0; it < nIter; ++it) {
        if (it + 1 < nIter) {
            const int k1 = (it + 1) << 5;
            gload_lds16(gA0 + k1, As[cur ^ 1] + t * 8);
            gload_lds16(gA1 + k1, As[cur ^ 1] + 4096 + t * 8);
            gload_lds16(gB0 + k1, Bs[cur ^ 1] + t * 8);
            asm volatile("s_waitcnt vmcnt(3)" ::: "memory");
        } else {
            asm volatile("s_waitcnt vmcnt(0)" ::: "memory");
        }
        __builtin_amdgcn_s_barrier();
        __builtin_amdgcn_sched_barrier(0);
        bf16x8 af[4], bfr[4];
#pragma unroll
        for (int i = 0; i < 4; ++i)
            af[i] = *(const bf16x8*)(As[cur] + (ra + i * 16) * 32 + kos);
#pragma unroll
        for (int j = 0; j < 4; ++j)
            bfr[j] = *(const bf16x8*)(Bs[cur] + (rb + ((j & 1) * 16 + (j >> 1) * 32)) * 32 + kos);
        asm volatile("s_waitcnt lgkmcnt(0)" ::: "memory");
        __builtin_amdgcn_sched_barrier(0);
        __builtin_amdgcn_s_barrier();
#pragma unroll
        for (int i = 0; i < 4; ++i)
#pragma unroll
            for (int j = 0; j < 4; ++j)
                acc[i][j] = __builtin_amdgcn_mfma_f32_16x16x32_bf16(af[i], bfr[j], acc[i][j], 0, 0, 0);
        cur ^= 1;
    }

    const int rowb = m0 + wr * 64 + ((lane >> 4) * 4);
    u16* Cb = (u16*)Cv;
#pragma unroll
    for (int j = 0; j < 4; ++j) {
        int col = n0 + wc * 64 + ((j & 1) * 16 + (j >> 1) * 32) + (lane & 15);
        float bj = bias[col];
#pragma unroll
        for (int i = 0; i < 4; ++i) {
            int rw = rowb + i * 16;
#pragma unroll
            for (int r = 0; r < 4; ++r) {
                float v = acc[i][j][r] + bj;
                if (MODE == 2) v = fmaxf(v, 0.f);
                Cb[(size_t)(rw + r) * N + col] = f2bu(v);
            }
        }
    }
}

// ---------------- MFMA GEMM, 128x128 tile, 256 thr (ffn2) ---------------------
// R10-verified loop + T2 swizzle + T1 XCD-bijective 1-D grid.
// MODE 3: ffn2 -> fp32 BCHW d_out = x1(bf16) + ls*(acc+bias)   (N=256)
template<int MODE>
__global__ __launch_bounds__(256) void k_mgemm128(
        const u16* __restrict__ A, const u16* __restrict__ Bt,
        const float* __restrict__ bias, void* __restrict__ Cv,
        int K, int N, const void* __restrict__ extra,
        const float* __restrict__ extra2, int grow0, int gy) {
    __shared__ __align__(16) u16 As[2][128 * 32];
    __shared__ __align__(16) u16 Bs[2][128 * 32];
    const int swz = xcd_swz(blockIdx.x, gridDim.x);
    const int mb = swz / gy, nb = swz - mb * gy;
    const int m0 = mb * 128, n0 = nb * 128;
    const int t = threadIdx.x, lane = t & 63;
    const int wv = t >> 6, wr = wv >> 1, wc = wv & 1;

    const int kc = (t & 3) ^ ((t >> 3) & 3);
    const u16* gA0 = A  + (size_t)(m0 + (t >> 2)) * K + kc * 8;
    const u16* gA1 = A  + (size_t)(m0 + 64 + (t >> 2)) * K + kc * 8;
    const u16* gB0 = Bt + (size_t)(n0 + (t >> 2)) * K + kc * 8;
    const u16* gB1 = Bt + (size_t)(n0 + 64 + (t >> 2)) * K + kc * 8;

    f32x4 acc[4][4] = {};
    const int ra = wr * 64 + (lane & 15);
    const int rb = wc * 64 + (lane & 15);
    const int kos = (((lane >> 4) ^ (lane >> 1)) & 3) * 8;
    const int nIter = K >> 5;

    gload_lds16(gA0, As[0] + t * 8);
    gload_lds16(gA1, As[0] + 2048 + t * 8);
    gload_lds16(gB0, Bs[0] + t * 8);
    gload_lds16(gB1, Bs[0] + 2048 + t * 8);

    int cur = 0;
    for (int it = 0; it < nIter; ++it) {
        if (it + 1 < nIter) {
            const int k1 = (it + 1) << 5;
            gload_lds16(gA0 + k1, As[cur ^ 1] + t * 8);
            gload_lds16(gA1 + k1, As[cur ^ 1] + 2048 + t * 8);
            gload_lds16(gB0 + k1, Bs[cur ^ 1] + t * 8);
            gload_lds16(gB1 + k1, Bs[cur ^ 1] + 2048 + t * 8);
            asm volatile("s_waitcnt vmcnt(4)" ::: "memory");
        } else {
            asm volatile("s_waitcnt vmcnt(0)" ::: "memory");
        }
        __builtin_amdgcn_s_barrier();
        __builtin_amdgcn_sched_barrier(0);
        bf16x8 af[4], bfr[4];
#pragma unroll
        for (int i = 0; i < 4; ++i)
            af[i] = *(const bf16x8*)(As[cur] + (ra + i * 16) * 32 + kos);
#pragma unroll
        for (int j = 0; j < 4; ++j)
            bfr[j] = *(const bf16x8*)(Bs[cur] + (rb + j * 16) * 32 + kos);
        asm volatile("s_waitcnt lgkmcnt(0)" ::: "memory");
        __builtin_amdgcn_sched_barrier(0);
        __builtin_amdgcn_s_barrier();
#pragma unroll
        for (int i = 0; i < 4; ++i)
#pragma unroll
            for (int j = 0; j < 4; ++j)
                acc[i][j] = __builtin_amdgcn_mfma_f32_16x16x32_bf16(af[i], bfr[j], acc[i][j], 0, 0, 0);
        cur ^= 1;
    }

    const int colb = n0 + wc * 64 + (lane & 15);
    const int rowb = m0 + wr * 64 + ((lane >> 4) * 4);

    float* C = (float*)Cv;
    const u16* xr = (const u16*)extra;       // x1 bf16
#pragma unroll
    for (int j = 0; j < 4; ++j) {
        int col = colb + j * 16;
        float bj = bias[col], lj = extra2[col];
#pragma unroll
        for (int i = 0; i < 4; ++i) {
            int g  = grow0 + rowb + i * 16;   // 4-row pack never crosses batch
            int b  = g / HW, hw = g - b * HW;
            f32x4 o;
#pragma unroll
            for (int r = 0; r < 4; ++r)
                o[r] = bu2f(xr[(size_t)(g + r) * 256 + col]) + lj * (acc[i][j][r] + bj);
            *(f32x4*)(C + ((size_t)(b * 256 + col)) * HW + hw) = o;
        }
    }
}

// ---------------- fused attention + proj: one BLOCK per window ----------------
// Attention phase identical to R16/R17-verified. Proj phase REWORKED:
// each wave's 32x256 weight slice lives in REGISTERS (64 VGPR, natural
// fragment layout, loaded after attention when s/qf/kf die) -> the proj loop
// is pure {ds_read o_t + MFMA} x8 with ZERO barriers / vmcnt waits (compiler
// emits fine-grained lgkmcnt). LDS: phase A Pl 58,608 B; phase B o_t 33,792 B.
__global__ __launch_bounds__(512) void k_attnproj(const u16* __restrict__ qkv,
        const u16* __restrict__ wpt, const float* __restrict__ pbias,
        u16* __restrict__ x1b) {
    __shared__ __align__(16) u16 U[29304];   // 58,608 B
    const int wv = threadIdx.x >> 6, lane = threadIdx.x & 63;
    const int win = blockIdx.x, head = wv, wi = win & 63;
    const int rowbase = win * LWIN;
    const int g = lane >> 4, c = lane & 15, ko = g * 8;
    const u16* qb = qkv + (size_t)rowbase * 768 + head * 32;
    u16* pl = U + wv * (LWIN * 72);

    bf16x8 vb[2][2];
#pragma unroll
    for (int j2 = 0; j2 < 2; ++j2) {
        int d = j2 * 16 + c;
#pragma unroll
        for (int h = 0; h < 2; ++h)
#pragma unroll
            for (int tt = 0; tt < 8; ++tt) {
                int k = h * 32 + ko + tt;
                u16 val = (k < LWIN) ? qb[(size_t)k * 768 + 512 + d] : (u16)0;
                vb[j2][h][tt] = __builtin_bit_cast(__bf16, val);
            }
    }

    bf16x8 qf[4], kf[4];
#pragma unroll
    for (int i = 0; i < 4; ++i) {
        int r0 = i * 16 + c; if (r0 > 48) r0 = 48;
        qf[i] = *(const bf16x8*)(qb + (size_t)r0 * 768 + ko);
        kf[i] = *(const bf16x8*)(qb + (size_t)r0 * 768 + 256 + ko);
    }
    f32x4 s[4][4] = {};
    __builtin_amdgcn_s_setprio(1);
#pragma unroll
    for (int i = 0; i < 4; ++i)
#pragma unroll
        for (int j = 0; j < 4; ++j)
            s[i][j] = __builtin_amdgcn_mfma_f32_16x16x32_bf16(qf[i], kf[j], s[i][j], 0, 0, 0);
    __builtin_amdgcn_s_setprio(0);

    const int wh7 = (wi >> 3) * 7, ww7 = (wi & 7) * 7;
    int idj[4]; bool jok[4];
#pragma unroll
    for (int j = 0; j < 4; ++j) {
        int col = j * 16 + c;
        jok[j] = col < LWIN;
        int p = jok[j] ? col : 48;
        idj[j] = region_of(wh7 + p / 7) * 3 + region_of(ww7 + p % 7);
    }
#pragma unroll
    for (int i = 0; i < 4; ++i) {
#pragma unroll
        for (int r = 0; r < 4; ++r) {
            int row = i * 16 + g * 4 + r;
            int p = row < LWIN ? row : 48;
            int idi = region_of(wh7 + p / 7) * 3 + region_of(ww7 + p % 7);
            float mx = -1e30f;
#pragma unroll
            for (int j = 0; j < 4; ++j) {
                float tv = jok[j] ? fmaf(s[i][j][r], 0.17677669529663687f,
                                         (idi == idj[j]) ? 0.f : -100.f)
                                  : -1e30f;
                s[i][j][r] = tv;
                mx = fmaxf(mx, tv);
            }
            for (int o = 8; o; o >>= 1) mx = fmaxf(mx, __shfl_xor(mx, o));
            float ps = 0.f;
#pragma unroll
            for (int j = 0; j < 4; ++j) {
                float e = __expf(s[i][j][r] - mx);
                s[i][j][r] = e; ps += e;
            }
            for (int o = 8; o; o >>= 1) ps += __shfl_xor(ps, o);
            float inv = 1.f / ps;
            if (row < LWIN) {
#pragma unroll
                for (int j = 0; j < 4; ++j)
                    pl[row * 72 + j * 16 + c] = f2bu(s[i][j][r] * inv);
            }
        }
    }
    // per-wave pl: compiler-inserted lgkmcnt orders write->read within the wave

    f32x4 o[4][2] = {};
    __builtin_amdgcn_s_setprio(1);
#pragma unroll
    for (int i = 0; i < 4; ++i) {
        bf16x8 pa0 = *(const bf16x8*)(&pl[(i * 16 + c) * 72 + ko]);
        bf16x8 pa1 = *(const bf16x8*)(&pl[(i * 16 + c) * 72 + ko + 32]);
#pragma unroll
        for (int j2 = 0; j2 < 2; ++j2) {
            o[i][j2] = __builtin_amdgcn_mfma_f32_16x16x32_bf16(pa0, vb[j2][0], o[i][j2], 0, 0, 0);
            o[i][j2] = __builtin_amdgcn_mfma_f32_16x16x32_bf16(pa1, vb[j2][1], o[i][j2], 0, 0, 0);
        }
    }
    __builtin_amdgcn_s_setprio(0);

    __syncthreads();        // all waves done reading Pl -> U reusable as o_t

    // --- weight slice -> registers (no swizzle: regs have no banks) ---
    bf16x8 wreg[8][2];
#pragma unroll
    for (int it = 0; it < 8; ++it)
#pragma unroll
        for (int j2 = 0; j2 < 2; ++j2)
            wreg[it][j2] = *(const bf16x8*)(wpt +
                (size_t)(wv * 32 + j2 * 16 + c) * 256 + it * 32 + ko);

    // --- o_t = U (64 x 264: row stride 528 B -> 2-way banks, free) ---
    u16* o_t = U;
#pragma unroll
    for (int i = 0; i < 4; ++i)
#pragma unroll
        for (int r = 0; r < 4; ++r) {
            int row = i * 16 + g * 4 + r;
            if (row < LWIN) {
#pragma unroll
                for (int j2 = 0; j2 < 2; ++j2)
                    o_t[row * 264 + head * 32 + j2 * 16 + c] = f2bu(o[i][j2][r]);
            }
        }
    __syncthreads();        // o_t complete (rows >= 49 stale-garbage: discarded)

    // --- proj: 8 x {4 ds_read + 8 MFMA}, no barriers, weights in regs ---
    f32x4 acc2[4][2] = {};
#pragma unroll
    for (int it = 0; it < 8; ++it) {
        bf16x8 af[4];
#pragma unroll
        for (int i = 0; i < 4; ++i)
            af[i] = *(const bf16x8*)(o_t + (i * 16 + c) * 264 + it * 32 + ko);
        __builtin_amdgcn_s_setprio(1);
#pragma unroll
        for (int i = 0; i < 4; ++i)
#pragma unroll
            for (int j2 = 0; j2 < 2; ++j2)
                acc2[i][j2] = __builtin_amdgcn_mfma_f32_16x16x32_bf16(af[i], wreg[it][j2], acc2[i][j2], 0, 0, 0);
        __builtin_amdgcn_s_setprio(0);
    }

    // --- epilogue: scatter to x1b (proj_out) via row2tok, + bias ---
#pragma unroll
    for (int j2 = 0; j2 < 2; ++j2) {
        int col = wv * 32 + j2 * 16 + c;
        float bj = pbias[col];
#pragma unroll
        for (int i = 0; i < 4; ++i)
#pragma unroll
            for (int r = 0; r < 4; ++r) {
                int row = i * 16 + g * 4 + r;
                if (row < LWIN) {
                    int tok = row2tok(rowbase + row);
                    x1b[(size_t)tok * 256 + col] = f2bu(acc2[i][j2][r] + bj);
                }
            }
    }
}

extern "C" void kernel_launch(void* const* d_in, const int* in_sizes, int n_in,
                              void* d_out, int out_size, void* d_ws, size_t ws_size,
                              hipStream_t stream) {
    const float* x      = (const float*)d_in[0];
    const float* ln1_g  = (const float*)d_in[1];
    const float* ln1_b  = (const float*)d_in[2];
    const float* ln2_g  = (const float*)d_in[3];
    const float* ln2_b  = (const float*)d_in[4];
    const float* qkv_w  = (const float*)d_in[5];
    const float* qkv_b  = (const float*)d_in[6];
    const float* proj_w = (const float*)d_in[7];
    const float* proj_b = (const float*)d_in[8];
    const float* ffn_w1 = (const float*)d_in[9];
    const float* ffn_b1 = (const float*)d_in[10];
    const float* ffn_w2 = (const float*)d_in[11];
    const float* ffn_b2 = (const float*)d_in[12];
    const float* lscale = (const float*)d_in[13];

    // workspace: total 104,333,312 B (layout unchanged since R6)
    char* wsb = (char*)d_ws;
    u16* wqt  = (u16*)(wsb);
    u16* wpt  = (u16*)(wsb + 393216);
    u16* w1t  = (u16*)(wsb + 524288);
    u16* w2t  = (u16*)(wsb + 1048576);
    u16* P    = (u16*)(wsb + 1572864);
    char* Qb  = wsb + 27262976;
    u16* qkvb = (u16*)Qb;
    u16* x1b  = (u16*)Qb;
    u16* f1c  = (u16*)(Qb + 25690112);

    k_wconv_all<<<768, 256, 0, stream>>>(qkv_w, wqt, proj_w, wpt, ffn_w1, w1t, ffn_w2, w2t);

    k_ln1<<<16 * 98, 256, 0, stream>>>(x, ln1_g, ln1_b, P);
    // qkv: 196 m-blocks x 6 n-blocks, XCD-swizzled 1-D grid (1176 % 8 == 0)
    k_mgemm256<0><<<1176, 512, 0, stream>>>(P, wqt, qkv_b, qkvb, 256, 768, 6);
    // fused attention + proj -> proj_out (x1b, token-scattered bf16)
    k_attnproj<<<1024, 512, 0, stream>>>(qkvb, wpt, proj_b, x1b);
    // x1 = proj_out + transpose(x) (in-place), h2 = LN2(x1) -> P
    k_ln2t<<<16 * 98, 256, 0, stream>>>(x, x1b, ln2_g, ln2_b, P);
    for (int c = 0; c < 2; ++c) {
        // ffn1: 98 x 8 = 784 (784 % 8 == 0)
        k_mgemm256<2><<<784, 512, 0, stream>>>(P + (size_t)c * FCH * 256, w1t, ffn_b1,
                                               f1c, 256, 1024, 8);
        // ffn2: 196 x 2 = 392 (392 % 8 == 0)
        k_mgemm128<3><<<392, 256, 0, stream>>>(f1c, w2t, ffn_b2, d_out, 1024, 256,
                                               x1b, lscale, c * FCH, 2);
    }
}